// Round 2
// baseline (547.037 us; speedup 1.0000x reference)
//
#include <hip/hip_runtime.h>
#include <stdint.h>

#define EMB   768
#define BATCH 8
#define SEQ   2048
#define ROWS  (BATCH*SEQ)     // 16384
#define EPS   1e-5f

#define BM 128
#define BN 128
#define BK 32

typedef _Float16 half8 __attribute__((ext_vector_type(8)));
typedef _Float16 half4 __attribute__((ext_vector_type(4)));
typedef float    floatx4 __attribute__((ext_vector_type(4)));

// async global->LDS, 16B per lane (global_load_lds_dwordx4).
// LDS dest is wave-uniform base + lane*16 — tid*16 mapping satisfies this.
__device__ __forceinline__ void g2l16(const void* g, void* l) {
    __builtin_amdgcn_global_load_lds(
        (const __attribute__((address_space(1))) unsigned int*)g,
        (__attribute__((address_space(3))) unsigned int*)l,
        16, 0, 0);
}

// ---------------- LayerNorm: f32 in -> f16 hi/lo split ----------------
// one wave per row (768 elems, 3 float4/lane), wave shuffle reduction
__global__ __launch_bounds__(256) void ln_kernel(
    const float* __restrict__ h,
    const float* __restrict__ gamma,
    const float* __restrict__ beta,
    _Float16* __restrict__ hn_hi,
    _Float16* __restrict__ hn_lo)
{
    int row  = blockIdx.x * 4 + (threadIdx.x >> 6);
    int lane = threadIdx.x & 63;
    const float4* hr4 = (const float4*)(h + (size_t)row * EMB);
    float4 x[3];
    float s1 = 0.f, s2 = 0.f;
#pragma unroll
    for (int j = 0; j < 3; j++) {
        x[j] = hr4[lane + j * 64];
        s1 += x[j].x + x[j].y + x[j].z + x[j].w;
        s2 += x[j].x * x[j].x + x[j].y * x[j].y + x[j].z * x[j].z + x[j].w * x[j].w;
    }
#pragma unroll
    for (int s = 1; s < 64; s <<= 1) {
        s1 += __shfl_xor(s1, s, 64);
        s2 += __shfl_xor(s2, s, 64);
    }
    float mu  = s1 * (1.0f / EMB);
    float var = s2 * (1.0f / EMB) - mu * mu;
    float rs  = rsqrtf(var + EPS);
    _Float16* oh = hn_hi + (size_t)row * EMB;
    _Float16* ol = hn_lo + (size_t)row * EMB;
#pragma unroll
    for (int j = 0; j < 3; j++) {
        int e = (lane + j * 64) * 4;
        float4 g = ((const float4*)gamma)[lane + j * 64];
        float4 b = ((const float4*)beta)[lane + j * 64];
        float v[4] = {
            (x[j].x - mu) * rs * g.x + b.x,
            (x[j].y - mu) * rs * g.y + b.y,
            (x[j].z - mu) * rs * g.z + b.z,
            (x[j].w - mu) * rs * g.w + b.w };
        half4 vh, vl;
#pragma unroll
        for (int t = 0; t < 4; t++) {
            _Float16 hi = (_Float16)v[t];
            vh[t] = hi;
            vl[t] = (_Float16)(v[t] - (float)hi);
        }
        *(half4*)(oh + e) = vh;
        *(half4*)(ol + e) = vl;
    }
}

// ---------------- transpose weights: w[d][e] f32 -> wT[e][d] f16 hi/lo ----------------
__global__ __launch_bounds__(256) void transpose_kernel(
    const float* __restrict__ wq,
    const float* __restrict__ wk,
    _Float16* __restrict__ wqT_hi, _Float16* __restrict__ wqT_lo,
    _Float16* __restrict__ wkT_hi, _Float16* __restrict__ wkT_lo)
{
    __shared__ float tile[32][33];
    const float* src = (blockIdx.z == 0) ? wq : wk;
    _Float16* dh     = (blockIdx.z == 0) ? wqT_hi : wkT_hi;
    _Float16* dl     = (blockIdx.z == 0) ? wqT_lo : wkT_lo;
    int db = blockIdx.y * 32, eb = blockIdx.x * 32;
    int tx = threadIdx.x & 31, ty = threadIdx.x >> 5;  // 32 x 8
#pragma unroll
    for (int r = 0; r < 32; r += 8)
        tile[ty + r][tx] = src[(size_t)(db + ty + r) * EMB + eb + tx];
    __syncthreads();
#pragma unroll
    for (int r = 0; r < 32; r += 8) {
        float v = tile[tx][ty + r];
        _Float16 hi = (_Float16)v;
        dh[(size_t)(eb + ty + r) * EMB + db + tx] = hi;
        dl[(size_t)(eb + ty + r) * EMB + db + tx] = (_Float16)(v - (float)hi);
    }
}

// ---------------- projection GEMM (f16x2 3-pass): q/k = hn @ W + b ----------------
__global__ __launch_bounds__(256) void proj_kernel(
    const _Float16* __restrict__ hn_hi, const _Float16* __restrict__ hn_lo,
    const _Float16* __restrict__ wqT_hi, const _Float16* __restrict__ wqT_lo,
    const _Float16* __restrict__ wkT_hi, const _Float16* __restrict__ wkT_lo,
    const float* __restrict__ bq, const float* __restrict__ bk,
    _Float16* __restrict__ q_hi, _Float16* __restrict__ q_lo,
    _Float16* __restrict__ k_hi, _Float16* __restrict__ k_lo)
{
    __shared__ __attribute__((aligned(16))) _Float16 Ah_s[BM * BK];
    __shared__ __attribute__((aligned(16))) _Float16 Al_s[BM * BK];
    __shared__ __attribute__((aligned(16))) _Float16 Bh_s[BN * BK];
    __shared__ __attribute__((aligned(16))) _Float16 Bl_s[BN * BK];

    const _Float16* Bh = (blockIdx.z == 0) ? wqT_hi : wkT_hi;
    const _Float16* Bl = (blockIdx.z == 0) ? wqT_lo : wkT_lo;
    const float* bias  = (blockIdx.z == 0) ? bq : bk;
    _Float16* Ch       = (blockIdx.z == 0) ? q_hi : k_hi;
    _Float16* Cl       = (blockIdx.z == 0) ? q_lo : k_lo;

    int rowbase = blockIdx.y * BM;
    int colbase = blockIdx.x * BN;
    int tid  = threadIdx.x;
    int lane = tid & 63, wave = tid >> 6;
    int wrow = (wave >> 1) * 64, wcol = (wave & 1) * 64;

    floatx4 acc[4][4];
#pragma unroll
    for (int i = 0; i < 4; i++)
#pragma unroll
        for (int j = 0; j < 4; j++) acc[i][j] = (floatx4){0.f, 0.f, 0.f, 0.f};

    size_t arow = (size_t)(rowbase + tid / 4) * EMB;
    size_t brow = (size_t)(colbase + tid / 4) * EMB;
    int    boff = (tid % 4) * 16;
    const char* gAh = (const char*)(hn_hi + arow) + boff;
    const char* gAl = (const char*)(hn_lo + arow) + boff;
    const char* gBh = (const char*)(Bh + brow) + boff;
    const char* gBl = (const char*)(Bl + brow) + boff;
    char* lAh = (char*)Ah_s + tid * 16;
    char* lAl = (char*)Al_s + tid * 16;
    char* lBh = (char*)Bh_s + tid * 16;
    char* lBl = (char*)Bl_s + tid * 16;
    const size_t half_stride = (size_t)64 * EMB * 2;  // 64 rows of f16

    for (int k0 = 0; k0 < EMB; k0 += BK) {
        __syncthreads();
        g2l16(gAh, lAh); g2l16(gAh + half_stride, lAh + 4096);
        g2l16(gAl, lAl); g2l16(gAl + half_stride, lAl + 4096);
        g2l16(gBh, lBh); g2l16(gBh + half_stride, lBh + 4096);
        g2l16(gBl, lBl); g2l16(gBl + half_stride, lBl + 4096);
        gAh += 64; gAl += 64; gBh += 64; gBl += 64;
        __syncthreads();

        half8 ah[4], al[4], bh[4], bl[4];
#pragma unroll
        for (int i = 0; i < 4; i++) {
            int off = (wrow + i * 16 + (lane & 15)) * 64 + (lane >> 4) * 16;
            ah[i] = *(const half8*)((const char*)Ah_s + off);
            al[i] = *(const half8*)((const char*)Al_s + off);
        }
#pragma unroll
        for (int j = 0; j < 4; j++) {
            int off = (wcol + j * 16 + (lane & 15)) * 64 + (lane >> 4) * 16;
            bh[j] = *(const half8*)((const char*)Bh_s + off);
            bl[j] = *(const half8*)((const char*)Bl_s + off);
        }
#pragma unroll
        for (int i = 0; i < 4; i++)
#pragma unroll
            for (int j = 0; j < 4; j++) {
                acc[i][j] = __builtin_amdgcn_mfma_f32_16x16x32_f16(ah[i], bh[j], acc[i][j], 0, 0, 0);
                acc[i][j] = __builtin_amdgcn_mfma_f32_16x16x32_f16(ah[i], bl[j], acc[i][j], 0, 0, 0);
                acc[i][j] = __builtin_amdgcn_mfma_f32_16x16x32_f16(al[i], bh[j], acc[i][j], 0, 0, 0);
            }
    }

    // epilogue: add bias, split f32 -> f16 hi/lo.  C/D: col=lane&15, row=quad*4+reg
#pragma unroll
    for (int j = 0; j < 4; j++) {
        int col = colbase + wcol + j * 16 + (lane & 15);
        float b = bias[col];
#pragma unroll
        for (int i = 0; i < 4; i++) {
#pragma unroll
            for (int r = 0; r < 4; r++) {
                int row = rowbase + wrow + i * 16 + (lane >> 4) * 4 + r;
                float v = acc[i][j][r] + b;
                _Float16 hi = (_Float16)v;
                Ch[(size_t)row * EMB + col] = hi;
                Cl[(size_t)row * EMB + col] = (_Float16)(v - (float)hi);
            }
        }
    }
}

// ---------------- scores GEMM (f16x2 3-pass) + partial softmax ----------------
// per block: S = q_tile @ k_tile^T (128x128); per-row block-local max m and sum l;
// writes ptilde=exp(s-m) f32 to out, (m,l) to state.
__global__ __launch_bounds__(256) void scores_kernel(
    const _Float16* __restrict__ q_hi, const _Float16* __restrict__ q_lo,
    const _Float16* __restrict__ k_hi, const _Float16* __restrict__ k_lo,
    float* __restrict__ out,
    float2* __restrict__ state)
{
    __shared__ __attribute__((aligned(16))) _Float16 Ah_s[BM * BK];
    __shared__ __attribute__((aligned(16))) _Float16 Al_s[BM * BK];
    __shared__ __attribute__((aligned(16))) _Float16 Bh_s[BN * BK];
    __shared__ __attribute__((aligned(16))) _Float16 Bl_s[BN * BK];
    __shared__ float red[128][2];

    int b = blockIdx.z;
    size_t base = (size_t)b * SEQ * EMB;
    int rowbase = blockIdx.y * BM;
    int colbase = blockIdx.x * BN;
    int tid  = threadIdx.x;
    int lane = tid & 63, wave = tid >> 6;
    int wrow = (wave >> 1) * 64, wcol = (wave & 1) * 64;

    floatx4 acc[4][4];
#pragma unroll
    for (int i = 0; i < 4; i++)
#pragma unroll
        for (int j = 0; j < 4; j++) acc[i][j] = (floatx4){0.f, 0.f, 0.f, 0.f};

    size_t arow = base + (size_t)(rowbase + tid / 4) * EMB;
    size_t brow = base + (size_t)(colbase + tid / 4) * EMB;
    int    boff = (tid % 4) * 16;
    const char* gAh = (const char*)(q_hi + arow) + boff;
    const char* gAl = (const char*)(q_lo + arow) + boff;
    const char* gBh = (const char*)(k_hi + brow) + boff;
    const char* gBl = (const char*)(k_lo + brow) + boff;
    char* lAh = (char*)Ah_s + tid * 16;
    char* lAl = (char*)Al_s + tid * 16;
    char* lBh = (char*)Bh_s + tid * 16;
    char* lBl = (char*)Bl_s + tid * 16;
    const size_t half_stride = (size_t)64 * EMB * 2;

    for (int k0 = 0; k0 < EMB; k0 += BK) {
        __syncthreads();
        g2l16(gAh, lAh); g2l16(gAh + half_stride, lAh + 4096);
        g2l16(gAl, lAl); g2l16(gAl + half_stride, lAl + 4096);
        g2l16(gBh, lBh); g2l16(gBh + half_stride, lBh + 4096);
        g2l16(gBl, lBl); g2l16(gBl + half_stride, lBl + 4096);
        gAh += 64; gAl += 64; gBh += 64; gBl += 64;
        __syncthreads();

        half8 ah[4], al[4], bh[4], bl[4];
#pragma unroll
        for (int i = 0; i < 4; i++) {
            int off = (wrow + i * 16 + (lane & 15)) * 64 + (lane >> 4) * 16;
            ah[i] = *(const half8*)((const char*)Ah_s + off);
            al[i] = *(const half8*)((const char*)Al_s + off);
        }
#pragma unroll
        for (int j = 0; j < 4; j++) {
            int off = (wcol + j * 16 + (lane & 15)) * 64 + (lane >> 4) * 16;
            bh[j] = *(const half8*)((const char*)Bh_s + off);
            bl[j] = *(const half8*)((const char*)Bl_s + off);
        }
#pragma unroll
        for (int i = 0; i < 4; i++)
#pragma unroll
            for (int j = 0; j < 4; j++) {
                acc[i][j] = __builtin_amdgcn_mfma_f32_16x16x32_f16(ah[i], bh[j], acc[i][j], 0, 0, 0);
                acc[i][j] = __builtin_amdgcn_mfma_f32_16x16x32_f16(ah[i], bl[j], acc[i][j], 0, 0, 0);
                acc[i][j] = __builtin_amdgcn_mfma_f32_16x16x32_f16(al[i], bh[j], acc[i][j], 0, 0, 0);
            }
    }

    // ---- softmax partial epilogue ----
    float m1[4][4];
#pragma unroll
    for (int i = 0; i < 4; i++)
#pragma unroll
        for (int r = 0; r < 4; r++) {
            float m = fmaxf(fmaxf(acc[i][0][r], acc[i][1][r]), fmaxf(acc[i][2][r], acc[i][3][r]));
#pragma unroll
            for (int s = 1; s < 16; s <<= 1) m = fmaxf(m, __shfl_xor(m, s, 64));
            m1[i][r] = m;
        }
    if ((lane & 15) == 0) {
#pragma unroll
        for (int i = 0; i < 4; i++)
#pragma unroll
            for (int r = 0; r < 4; r++)
                red[wrow + i * 16 + (lane >> 4) * 4 + r][wave & 1] = m1[i][r];
    }
    __syncthreads();
    float mrow[4][4];
#pragma unroll
    for (int i = 0; i < 4; i++)
#pragma unroll
        for (int r = 0; r < 4; r++) {
            int rr = wrow + i * 16 + (lane >> 4) * 4 + r;
            mrow[i][r] = fmaxf(red[rr][0], red[rr][1]);
        }
    __syncthreads();

    float ls[4][4];
#pragma unroll
    for (int i = 0; i < 4; i++)
#pragma unroll
        for (int r = 0; r < 4; r++) {
            float s = 0.f;
#pragma unroll
            for (int j = 0; j < 4; j++) {
                float e = __expf(acc[i][j][r] - mrow[i][r]);
                acc[i][j][r] = e;
                s += e;
            }
#pragma unroll
            for (int sh = 1; sh < 16; sh <<= 1) s += __shfl_xor(s, sh, 64);
            ls[i][r] = s;
        }
    if ((lane & 15) == 0) {
#pragma unroll
        for (int i = 0; i < 4; i++)
#pragma unroll
            for (int r = 0; r < 4; r++)
                red[wrow + i * 16 + (lane >> 4) * 4 + r][wave & 1] = ls[i][r];
    }
    __syncthreads();

    // write ptilde (f32)
    size_t outbase = (size_t)b * SEQ * SEQ;
#pragma unroll
    for (int i = 0; i < 4; i++)
#pragma unroll
        for (int j = 0; j < 4; j++)
#pragma unroll
            for (int r = 0; r < 4; r++) {
                int row = rowbase + wrow + i * 16 + (lane >> 4) * 4 + r;
                int col = colbase + wcol + j * 16 + (lane & 15);
                out[outbase + (size_t)row * SEQ + col] = acc[i][j][r];
            }

    // write per-(row, colblock) state
    if ((wave & 1) == 0 && (lane & 15) == 0) {
#pragma unroll
        for (int i = 0; i < 4; i++)
#pragma unroll
            for (int r = 0; r < 4; r++) {
                int rr = wrow + i * 16 + (lane >> 4) * 4 + r;     // local row
                float l = red[rr][0] + red[rr][1];
                state[((size_t)b * SEQ + rowbase + rr) * 16 + blockIdx.x] =
                    make_float2(mrow[i][r], l);
            }
    }
}

// ---------------- fixup: global softmax normalize ----------------
// out[row][c] *= exp(m_t - M) / L  where t = c/128
__global__ __launch_bounds__(256) void fixup_kernel(
    float* __restrict__ out,
    const float2* __restrict__ state)
{
    int row  = blockIdx.x * 4 + (threadIdx.x >> 6);
    int lane = threadIdx.x & 63;
    const float2* st = state + (size_t)row * 16;
    float m[16], l[16];
    float M = -INFINITY;
#pragma unroll
    for (int t = 0; t < 16; t++) { float2 v = st[t]; m[t] = v.x; l[t] = v.y; M = fmaxf(M, m[t]); }
    float L = 0.f;
#pragma unroll
    for (int t = 0; t < 16; t++) { m[t] = __expf(m[t] - M); L += l[t] * m[t]; }
    float inv = 1.0f / L;
    float4* o4 = (float4*)(out + (size_t)row * SEQ);
#pragma unroll
    for (int c0 = 0; c0 < 8; c0++) {
        int i4 = c0 * 64 + lane;            // float4 index; element = i4*4
        float s = m[i4 >> 5] * inv;         // (i4*4)>>7 == i4>>5
        float4 v = o4[i4];
        v.x *= s; v.y *= s; v.z *= s; v.w *= s;
        o4[i4] = v;
    }
}

extern "C" void kernel_launch(void* const* d_in, const int* in_sizes, int n_in,
                              void* d_out, int out_size, void* d_ws, size_t ws_size,
                              hipStream_t stream)
{
    const float* h  = (const float*)d_in[0];
    const float* g  = (const float*)d_in[1];
    const float* be = (const float*)d_in[2];
    const float* wq = (const float*)d_in[3];
    const float* bq = (const float*)d_in[4];
    const float* wk = (const float*)d_in[5];
    const float* bk = (const float*)d_in[6];
    float* out = (float*)d_out;

    char* ws = (char*)d_ws;
    const size_t SZ = (size_t)ROWS * EMB * 2;          // 25,165,824 B per f16 plane
    _Float16* hn_hi  = (_Float16*)(ws);
    _Float16* hn_lo  = (_Float16*)(ws + SZ);
    _Float16* q_hi   = (_Float16*)(ws + 2 * SZ);
    _Float16* q_lo   = (_Float16*)(ws + 3 * SZ);
    _Float16* k_hi   = (_Float16*)(ws + 4 * SZ);
    _Float16* k_lo   = (_Float16*)(ws + 5 * SZ);
    char* wbase = ws + 6 * SZ;
    const size_t WSZ = (size_t)EMB * EMB * 2;          // 1,179,648 B
    _Float16* wqT_hi = (_Float16*)(wbase);
    _Float16* wqT_lo = (_Float16*)(wbase + WSZ);
    _Float16* wkT_hi = (_Float16*)(wbase + 2 * WSZ);
    _Float16* wkT_lo = (_Float16*)(wbase + 3 * WSZ);
    float2*   st     = (float2*)(wbase + 4 * WSZ);     // 16384*16*8 = 2 MB

    transpose_kernel<<<dim3(24, 24, 2), 256, 0, stream>>>(wq, wk, wqT_hi, wqT_lo, wkT_hi, wkT_lo);
    ln_kernel<<<dim3(ROWS / 4), 256, 0, stream>>>(h, g, be, hn_hi, hn_lo);
    proj_kernel<<<dim3(EMB / BN, ROWS / BM, 2), 256, 0, stream>>>(
        hn_hi, hn_lo, wqT_hi, wqT_lo, wkT_hi, wkT_lo, bq, bk, q_hi, q_lo, k_hi, k_lo);
    scores_kernel<<<dim3(SEQ / BN, SEQ / BM, BATCH), 256, 0, stream>>>(
        q_hi, q_lo, k_hi, k_lo, out, st);
    fixup_kernel<<<dim3(ROWS / 4), 256, 0, stream>>>(out, st);
}

// Round 3
// 498.339 us; speedup vs baseline: 1.0977x; 1.0977x over previous
//
#include <hip/hip_runtime.h>
#include <stdint.h>

#define EMB   768
#define BATCH 8
#define SEQ   2048
#define ROWS  (BATCH*SEQ)     // 16384
#define EPS   1e-5f

#define BM 128
#define BN 128
#define BK 32

typedef _Float16 half8 __attribute__((ext_vector_type(8)));
typedef _Float16 half4 __attribute__((ext_vector_type(4)));
typedef float    floatx4 __attribute__((ext_vector_type(4)));

// async global->LDS, 16B per lane (global_load_lds_dwordx4).
// LDS dest is wave-uniform base + lane*16 — tid*16 mapping satisfies this.
__device__ __forceinline__ void g2l16(const void* g, void* l) {
    __builtin_amdgcn_global_load_lds(
        (const __attribute__((address_space(1))) unsigned int*)g,
        (__attribute__((address_space(3))) unsigned int*)l,
        16, 0, 0);
}

// ---------------- LayerNorm: f32 in -> f16 hi/lo split ----------------
__global__ __launch_bounds__(256) void ln_kernel(
    const float* __restrict__ h,
    const float* __restrict__ gamma,
    const float* __restrict__ beta,
    _Float16* __restrict__ hn_hi,
    _Float16* __restrict__ hn_lo)
{
    int row  = blockIdx.x * 4 + (threadIdx.x >> 6);
    int lane = threadIdx.x & 63;
    const float4* hr4 = (const float4*)(h + (size_t)row * EMB);
    float4 x[3];
    float s1 = 0.f, s2 = 0.f;
#pragma unroll
    for (int j = 0; j < 3; j++) {
        x[j] = hr4[lane + j * 64];
        s1 += x[j].x + x[j].y + x[j].z + x[j].w;
        s2 += x[j].x * x[j].x + x[j].y * x[j].y + x[j].z * x[j].z + x[j].w * x[j].w;
    }
#pragma unroll
    for (int s = 1; s < 64; s <<= 1) {
        s1 += __shfl_xor(s1, s, 64);
        s2 += __shfl_xor(s2, s, 64);
    }
    float mu  = s1 * (1.0f / EMB);
    float var = s2 * (1.0f / EMB) - mu * mu;
    float rs  = rsqrtf(var + EPS);
    _Float16* oh = hn_hi + (size_t)row * EMB;
    _Float16* ol = hn_lo + (size_t)row * EMB;
#pragma unroll
    for (int j = 0; j < 3; j++) {
        int e = (lane + j * 64) * 4;
        float4 g = ((const float4*)gamma)[lane + j * 64];
        float4 b = ((const float4*)beta)[lane + j * 64];
        float v[4] = {
            (x[j].x - mu) * rs * g.x + b.x,
            (x[j].y - mu) * rs * g.y + b.y,
            (x[j].z - mu) * rs * g.z + b.z,
            (x[j].w - mu) * rs * g.w + b.w };
        half4 vh, vl;
#pragma unroll
        for (int t = 0; t < 4; t++) {
            _Float16 hi = (_Float16)v[t];
            vh[t] = hi;
            vl[t] = (_Float16)(v[t] - (float)hi);
        }
        *(half4*)(oh + e) = vh;
        *(half4*)(ol + e) = vl;
    }
}

// ---------------- transpose weights: w[d][e] f32 -> wT[e][d] f16 hi/lo ----------------
__global__ __launch_bounds__(256) void transpose_kernel(
    const float* __restrict__ wq,
    const float* __restrict__ wk,
    _Float16* __restrict__ wqT_hi, _Float16* __restrict__ wqT_lo,
    _Float16* __restrict__ wkT_hi, _Float16* __restrict__ wkT_lo)
{
    __shared__ float tile[32][33];
    const float* src = (blockIdx.z == 0) ? wq : wk;
    _Float16* dh     = (blockIdx.z == 0) ? wqT_hi : wkT_hi;
    _Float16* dl     = (blockIdx.z == 0) ? wqT_lo : wkT_lo;
    int db = blockIdx.y * 32, eb = blockIdx.x * 32;
    int tx = threadIdx.x & 31, ty = threadIdx.x >> 5;  // 32 x 8
#pragma unroll
    for (int r = 0; r < 32; r += 8)
        tile[ty + r][tx] = src[(size_t)(db + ty + r) * EMB + eb + tx];
    __syncthreads();
#pragma unroll
    for (int r = 0; r < 32; r += 8) {
        float v = tile[tx][ty + r];
        _Float16 hi = (_Float16)v;
        dh[(size_t)(eb + ty + r) * EMB + db + tx] = hi;
        dl[(size_t)(eb + ty + r) * EMB + db + tx] = (_Float16)(v - (float)hi);
    }
}

// ---------------- projection GEMM (f16x2 3-pass): q/k = hn @ W + b ----------------
// q only needs the hi plane downstream (scores drops ql); k needs hi+lo.
__global__ __launch_bounds__(256) void proj_kernel(
    const _Float16* __restrict__ hn_hi, const _Float16* __restrict__ hn_lo,
    const _Float16* __restrict__ wqT_hi, const _Float16* __restrict__ wqT_lo,
    const _Float16* __restrict__ wkT_hi, const _Float16* __restrict__ wkT_lo,
    const float* __restrict__ bq, const float* __restrict__ bk,
    _Float16* __restrict__ q_hi,
    _Float16* __restrict__ k_hi, _Float16* __restrict__ k_lo)
{
    __shared__ __attribute__((aligned(16))) _Float16 Ah_s[BM * BK];
    __shared__ __attribute__((aligned(16))) _Float16 Al_s[BM * BK];
    __shared__ __attribute__((aligned(16))) _Float16 Bh_s[BN * BK];
    __shared__ __attribute__((aligned(16))) _Float16 Bl_s[BN * BK];

    const bool is_q    = (blockIdx.z == 0);
    const _Float16* Bh = is_q ? wqT_hi : wkT_hi;
    const _Float16* Bl = is_q ? wqT_lo : wkT_lo;
    const float* bias  = is_q ? bq : bk;
    _Float16* Ch       = is_q ? q_hi : k_hi;

    int rowbase = blockIdx.y * BM;
    int colbase = blockIdx.x * BN;
    int tid  = threadIdx.x;
    int lane = tid & 63, wave = tid >> 6;
    int wrow = (wave >> 1) * 64, wcol = (wave & 1) * 64;

    floatx4 acc[4][4];
#pragma unroll
    for (int i = 0; i < 4; i++)
#pragma unroll
        for (int j = 0; j < 4; j++) acc[i][j] = (floatx4){0.f, 0.f, 0.f, 0.f};

    size_t arow = (size_t)(rowbase + tid / 4) * EMB;
    size_t brow = (size_t)(colbase + tid / 4) * EMB;
    int    boff = (tid % 4) * 16;
    const char* gAh = (const char*)(hn_hi + arow) + boff;
    const char* gAl = (const char*)(hn_lo + arow) + boff;
    const char* gBh = (const char*)(Bh + brow) + boff;
    const char* gBl = (const char*)(Bl + brow) + boff;
    char* lAh = (char*)Ah_s + tid * 16;
    char* lAl = (char*)Al_s + tid * 16;
    char* lBh = (char*)Bh_s + tid * 16;
    char* lBl = (char*)Bl_s + tid * 16;
    const size_t half_stride = (size_t)64 * EMB * 2;  // 64 rows of f16

    for (int k0 = 0; k0 < EMB; k0 += BK) {
        __syncthreads();
        g2l16(gAh, lAh); g2l16(gAh + half_stride, lAh + 4096);
        g2l16(gAl, lAl); g2l16(gAl + half_stride, lAl + 4096);
        g2l16(gBh, lBh); g2l16(gBh + half_stride, lBh + 4096);
        g2l16(gBl, lBl); g2l16(gBl + half_stride, lBl + 4096);
        gAh += 64; gAl += 64; gBh += 64; gBl += 64;
        __syncthreads();

        half8 ah[4], al[4], bh[4], bl[4];
#pragma unroll
        for (int i = 0; i < 4; i++) {
            int off = (wrow + i * 16 + (lane & 15)) * 64 + (lane >> 4) * 16;
            ah[i] = *(const half8*)((const char*)Ah_s + off);
            al[i] = *(const half8*)((const char*)Al_s + off);
        }
#pragma unroll
        for (int j = 0; j < 4; j++) {
            int off = (wcol + j * 16 + (lane & 15)) * 64 + (lane >> 4) * 16;
            bh[j] = *(const half8*)((const char*)Bh_s + off);
            bl[j] = *(const half8*)((const char*)Bl_s + off);
        }
#pragma unroll
        for (int i = 0; i < 4; i++)
#pragma unroll
            for (int j = 0; j < 4; j++) {
                acc[i][j] = __builtin_amdgcn_mfma_f32_16x16x32_f16(ah[i], bh[j], acc[i][j], 0, 0, 0);
                acc[i][j] = __builtin_amdgcn_mfma_f32_16x16x32_f16(ah[i], bl[j], acc[i][j], 0, 0, 0);
                acc[i][j] = __builtin_amdgcn_mfma_f32_16x16x32_f16(al[i], bh[j], acc[i][j], 0, 0, 0);
            }
    }

    // epilogue: add bias, split f32 -> f16 hi(/lo for k).  C/D: col=lane&15, row=quad*4+reg
#pragma unroll
    for (int j = 0; j < 4; j++) {
        int col = colbase + wcol + j * 16 + (lane & 15);
        float b = bias[col];
#pragma unroll
        for (int i = 0; i < 4; i++) {
#pragma unroll
            for (int r = 0; r < 4; r++) {
                int row = rowbase + wrow + i * 16 + (lane >> 4) * 4 + r;
                float v = acc[i][j][r] + b;
                _Float16 hi = (_Float16)v;
                Ch[(size_t)row * EMB + col] = hi;
                if (!is_q)
                    k_lo[(size_t)row * EMB + col] = (_Float16)(v - (float)hi);
            }
        }
    }
}

// ---------------- scores GEMM (2-pass: qh*kh + qh*kl) + partial softmax ----------------
// per block: S = q_tile @ k_tile^T (128x128); per-row block-local max m and sum l;
// writes ptilde=exp(s-m) f32 to out, (m,l) to state.
__global__ __launch_bounds__(256) void scores_kernel(
    const _Float16* __restrict__ q_hi,
    const _Float16* __restrict__ k_hi, const _Float16* __restrict__ k_lo,
    float* __restrict__ out,
    float2* __restrict__ state)
{
    __shared__ __attribute__((aligned(16))) _Float16 Ah_s[BM * BK];
    __shared__ __attribute__((aligned(16))) _Float16 Bh_s[BN * BK];
    __shared__ __attribute__((aligned(16))) _Float16 Bl_s[BN * BK];
    __shared__ float red[128][2];

    int b = blockIdx.z;
    size_t base = (size_t)b * SEQ * EMB;
    int rowbase = blockIdx.y * BM;
    int colbase = blockIdx.x * BN;
    int tid  = threadIdx.x;
    int lane = tid & 63, wave = tid >> 6;
    int wrow = (wave >> 1) * 64, wcol = (wave & 1) * 64;

    floatx4 acc[4][4];
#pragma unroll
    for (int i = 0; i < 4; i++)
#pragma unroll
        for (int j = 0; j < 4; j++) acc[i][j] = (floatx4){0.f, 0.f, 0.f, 0.f};

    size_t arow = base + (size_t)(rowbase + tid / 4) * EMB;
    size_t brow = base + (size_t)(colbase + tid / 4) * EMB;
    int    boff = (tid % 4) * 16;
    const char* gAh = (const char*)(q_hi + arow) + boff;
    const char* gBh = (const char*)(k_hi + brow) + boff;
    const char* gBl = (const char*)(k_lo + brow) + boff;
    char* lAh = (char*)Ah_s + tid * 16;
    char* lBh = (char*)Bh_s + tid * 16;
    char* lBl = (char*)Bl_s + tid * 16;
    const size_t half_stride = (size_t)64 * EMB * 2;

    for (int k0 = 0; k0 < EMB; k0 += BK) {
        __syncthreads();
        g2l16(gAh, lAh); g2l16(gAh + half_stride, lAh + 4096);
        g2l16(gBh, lBh); g2l16(gBh + half_stride, lBh + 4096);
        g2l16(gBl, lBl); g2l16(gBl + half_stride, lBl + 4096);
        gAh += 64; gBh += 64; gBl += 64;
        __syncthreads();

        half8 ah[4], bh[4], bl[4];
#pragma unroll
        for (int i = 0; i < 4; i++) {
            int off = (wrow + i * 16 + (lane & 15)) * 64 + (lane >> 4) * 16;
            ah[i] = *(const half8*)((const char*)Ah_s + off);
        }
#pragma unroll
        for (int j = 0; j < 4; j++) {
            int off = (wcol + j * 16 + (lane & 15)) * 64 + (lane >> 4) * 16;
            bh[j] = *(const half8*)((const char*)Bh_s + off);
            bl[j] = *(const half8*)((const char*)Bl_s + off);
        }
#pragma unroll
        for (int i = 0; i < 4; i++)
#pragma unroll
            for (int j = 0; j < 4; j++) {
                acc[i][j] = __builtin_amdgcn_mfma_f32_16x16x32_f16(ah[i], bh[j], acc[i][j], 0, 0, 0);
                acc[i][j] = __builtin_amdgcn_mfma_f32_16x16x32_f16(ah[i], bl[j], acc[i][j], 0, 0, 0);
            }
    }

    // ---- softmax partial epilogue ----
    float m1[4][4];
#pragma unroll
    for (int i = 0; i < 4; i++)
#pragma unroll
        for (int r = 0; r < 4; r++) {
            float m = fmaxf(fmaxf(acc[i][0][r], acc[i][1][r]), fmaxf(acc[i][2][r], acc[i][3][r]));
#pragma unroll
            for (int s = 1; s < 16; s <<= 1) m = fmaxf(m, __shfl_xor(m, s, 64));
            m1[i][r] = m;
        }
    if ((lane & 15) == 0) {
#pragma unroll
        for (int i = 0; i < 4; i++)
#pragma unroll
            for (int r = 0; r < 4; r++)
                red[wrow + i * 16 + (lane >> 4) * 4 + r][wave & 1] = m1[i][r];
    }
    __syncthreads();
    float mrow[4][4];
#pragma unroll
    for (int i = 0; i < 4; i++)
#pragma unroll
        for (int r = 0; r < 4; r++) {
            int rr = wrow + i * 16 + (lane >> 4) * 4 + r;
            mrow[i][r] = fmaxf(red[rr][0], red[rr][1]);
        }
    __syncthreads();

    float ls[4][4];
#pragma unroll
    for (int i = 0; i < 4; i++)
#pragma unroll
        for (int r = 0; r < 4; r++) {
            float s = 0.f;
#pragma unroll
            for (int j = 0; j < 4; j++) {
                float e = __expf(acc[i][j][r] - mrow[i][r]);
                acc[i][j][r] = e;
                s += e;
            }
#pragma unroll
            for (int sh = 1; sh < 16; sh <<= 1) s += __shfl_xor(s, sh, 64);
            ls[i][r] = s;
        }
    if ((lane & 15) == 0) {
#pragma unroll
        for (int i = 0; i < 4; i++)
#pragma unroll
            for (int r = 0; r < 4; r++)
                red[wrow + i * 16 + (lane >> 4) * 4 + r][wave & 1] = ls[i][r];
    }
    __syncthreads();

    // write ptilde (f32)
    size_t outbase = (size_t)b * SEQ * SEQ;
#pragma unroll
    for (int i = 0; i < 4; i++)
#pragma unroll
        for (int j = 0; j < 4; j++)
#pragma unroll
            for (int r = 0; r < 4; r++) {
                int row = rowbase + wrow + i * 16 + (lane >> 4) * 4 + r;
                int col = colbase + wcol + j * 16 + (lane & 15);
                out[outbase + (size_t)row * SEQ + col] = acc[i][j][r];
            }

    // write per-(row, colblock) state
    if ((wave & 1) == 0 && (lane & 15) == 0) {
#pragma unroll
        for (int i = 0; i < 4; i++)
#pragma unroll
            for (int r = 0; r < 4; r++) {
                int rr = wrow + i * 16 + (lane >> 4) * 4 + r;     // local row
                float l = red[rr][0] + red[rr][1];
                state[((size_t)b * SEQ + rowbase + rr) * 16 + blockIdx.x] =
                    make_float2(mrow[i][r], l);
            }
    }
}

// ---------------- fixup: global softmax normalize ----------------
__global__ __launch_bounds__(256) void fixup_kernel(
    float* __restrict__ out,
    const float2* __restrict__ state)
{
    int row  = blockIdx.x * 4 + (threadIdx.x >> 6);
    int lane = threadIdx.x & 63;
    const float2* st = state + (size_t)row * 16;
    float m[16], l[16];
    float M = -INFINITY;
#pragma unroll
    for (int t = 0; t < 16; t++) { float2 v = st[t]; m[t] = v.x; l[t] = v.y; M = fmaxf(M, m[t]); }
    float L = 0.f;
#pragma unroll
    for (int t = 0; t < 16; t++) { m[t] = __expf(m[t] - M); L += l[t] * m[t]; }
    float inv = 1.0f / L;
    float4* o4 = (float4*)(out + (size_t)row * SEQ);
#pragma unroll
    for (int c0 = 0; c0 < 8; c0++) {
        int i4 = c0 * 64 + lane;            // float4 index; element = i4*4
        float s = m[i4 >> 5] * inv;         // (i4*4)>>7 == i4>>5
        float4 v = o4[i4];
        v.x *= s; v.y *= s; v.z *= s; v.w *= s;
        o4[i4] = v;
    }
}

extern "C" void kernel_launch(void* const* d_in, const int* in_sizes, int n_in,
                              void* d_out, int out_size, void* d_ws, size_t ws_size,
                              hipStream_t stream)
{
    const float* h  = (const float*)d_in[0];
    const float* g  = (const float*)d_in[1];
    const float* be = (const float*)d_in[2];
    const float* wq = (const float*)d_in[3];
    const float* bq = (const float*)d_in[4];
    const float* wk = (const float*)d_in[5];
    const float* bk = (const float*)d_in[6];
    float* out = (float*)d_out;

    char* ws = (char*)d_ws;
    const size_t SZ = (size_t)ROWS * EMB * 2;          // 25,165,824 B per f16 plane
    _Float16* hn_hi  = (_Float16*)(ws);
    _Float16* hn_lo  = (_Float16*)(ws + SZ);
    _Float16* q_hi   = (_Float16*)(ws + 2 * SZ);
    _Float16* k_hi   = (_Float16*)(ws + 3 * SZ);
    _Float16* k_lo   = (_Float16*)(ws + 4 * SZ);
    char* wbase = ws + 5 * SZ;
    const size_t WSZ = (size_t)EMB * EMB * 2;          // 1,179,648 B
    _Float16* wqT_hi = (_Float16*)(wbase);
    _Float16* wqT_lo = (_Float16*)(wbase + WSZ);
    _Float16* wkT_hi = (_Float16*)(wbase + 2 * WSZ);
    _Float16* wkT_lo = (_Float16*)(wbase + 3 * WSZ);
    float2*   st     = (float2*)(wbase + 4 * WSZ);     // 16384*16*8 = 2 MB

    transpose_kernel<<<dim3(24, 24, 2), 256, 0, stream>>>(wq, wk, wqT_hi, wqT_lo, wkT_hi, wkT_lo);
    ln_kernel<<<dim3(ROWS / 4), 256, 0, stream>>>(h, g, be, hn_hi, hn_lo);
    proj_kernel<<<dim3(EMB / BN, ROWS / BM, 2), 256, 0, stream>>>(
        hn_hi, hn_lo, wqT_hi, wqT_lo, wkT_hi, wkT_lo, bq, bk, q_hi, k_hi, k_lo);
    scores_kernel<<<dim3(SEQ / BN, SEQ / BM, BATCH), 256, 0, stream>>>(
        q_hi, k_hi, k_lo, out, st);
    fixup_kernel<<<dim3(ROWS / 4), 256, 0, stream>>>(out, st);
}

// Round 4
// 471.263 us; speedup vs baseline: 1.1608x; 1.0575x over previous
//
#include <hip/hip_runtime.h>
#include <stdint.h>

#define EMB   768
#define BATCH 8
#define SEQ   2048
#define ROWS  (BATCH*SEQ)     // 16384
#define EPS   1e-5f

#define BM 128
#define BN 128
#define BK 32

typedef _Float16 half8 __attribute__((ext_vector_type(8)));
typedef _Float16 half4 __attribute__((ext_vector_type(4)));
typedef float    floatx4 __attribute__((ext_vector_type(4)));

// async global->LDS, 16B per lane (global_load_lds_dwordx4).
// LDS dest is wave-uniform base + lane*16 — tid*16 mapping satisfies this.
__device__ __forceinline__ void g2l16(const void* g, void* l) {
    __builtin_amdgcn_global_load_lds(
        (const __attribute__((address_space(1))) unsigned int*)g,
        (__attribute__((address_space(3))) unsigned int*)l,
        16, 0, 0);
}

// ---------------- split weights: f32 -> f16 hi/lo planes (no transpose needed) ----
__global__ __launch_bounds__(256) void split_w_kernel(
    const float* __restrict__ wq, const float* __restrict__ wk,
    _Float16* __restrict__ wq_hi, _Float16* __restrict__ wq_lo,
    _Float16* __restrict__ wk_hi, _Float16* __restrict__ wk_lo)
{
    const float* src = (blockIdx.y == 0) ? wq : wk;
    _Float16* dh     = (blockIdx.y == 0) ? wq_hi : wk_hi;
    _Float16* dl     = (blockIdx.y == 0) ? wq_lo : wk_lo;
    int i4 = blockIdx.x * 256 + threadIdx.x;           // 147456 float4s per matrix
    float4 v = ((const float4*)src)[i4];
    half4 vh, vl;
    float c[4] = {v.x, v.y, v.z, v.w};
#pragma unroll
    for (int t = 0; t < 4; t++) {
        _Float16 hi = (_Float16)c[t];
        vh[t] = hi;
        vl[t] = (_Float16)(c[t] - (float)hi);
    }
    ((half4*)dh)[i4] = vh;
    ((half4*)dl)[i4] = vl;
}

// ---------------- wtilde = Wk @ bq : wt[e] = dot(Wk[e][:], bq) ----------------
__global__ __launch_bounds__(256) void wtilde_kernel(
    const float* __restrict__ wk, const float* __restrict__ bq,
    float* __restrict__ wt)
{
    int row  = blockIdx.x * 4 + (threadIdx.x >> 6);
    int lane = threadIdx.x & 63;
    const float4* r4 = (const float4*)(wk + (size_t)row * EMB);
    const float4* b4 = (const float4*)bq;
    float s = 0.f;
#pragma unroll
    for (int j = 0; j < 3; j++) {
        float4 a = r4[lane + j * 64];
        float4 b = b4[lane + j * 64];
        s += a.x * b.x + a.y * b.y + a.z * b.z + a.w * b.w;
    }
#pragma unroll
    for (int sh = 1; sh < 64; sh <<= 1) s += __shfl_xor(s, sh, 64);
    if (lane == 0) wt[row] = s;
}

// ---------------- LayerNorm: f32 in -> f16 hi/lo split, + v = hn . wtilde -------
__global__ __launch_bounds__(256) void ln_kernel(
    const float* __restrict__ h,
    const float* __restrict__ gamma,
    const float* __restrict__ beta,
    const float* __restrict__ wt,
    _Float16* __restrict__ hn_hi,
    _Float16* __restrict__ hn_lo,
    float* __restrict__ v_out)
{
    int row  = blockIdx.x * 4 + (threadIdx.x >> 6);
    int lane = threadIdx.x & 63;
    const float4* hr4 = (const float4*)(h + (size_t)row * EMB);
    float4 x[3];
    float s1 = 0.f, s2 = 0.f;
#pragma unroll
    for (int j = 0; j < 3; j++) {
        x[j] = hr4[lane + j * 64];
        s1 += x[j].x + x[j].y + x[j].z + x[j].w;
        s2 += x[j].x * x[j].x + x[j].y * x[j].y + x[j].z * x[j].z + x[j].w * x[j].w;
    }
#pragma unroll
    for (int s = 1; s < 64; s <<= 1) {
        s1 += __shfl_xor(s1, s, 64);
        s2 += __shfl_xor(s2, s, 64);
    }
    float mu  = s1 * (1.0f / EMB);
    float var = s2 * (1.0f / EMB) - mu * mu;
    float rs  = rsqrtf(var + EPS);
    _Float16* oh = hn_hi + (size_t)row * EMB;
    _Float16* ol = hn_lo + (size_t)row * EMB;
    float vsum = 0.f;
#pragma unroll
    for (int j = 0; j < 3; j++) {
        int e4 = lane + j * 64;
        float4 g = ((const float4*)gamma)[e4];
        float4 b = ((const float4*)beta)[e4];
        float4 w = ((const float4*)wt)[e4];
        float v[4] = {
            (x[j].x - mu) * rs * g.x + b.x,
            (x[j].y - mu) * rs * g.y + b.y,
            (x[j].z - mu) * rs * g.z + b.z,
            (x[j].w - mu) * rs * g.w + b.w };
        vsum += v[0] * w.x + v[1] * w.y + v[2] * w.z + v[3] * w.w;
        half4 vh, vl;
#pragma unroll
        for (int t = 0; t < 4; t++) {
            _Float16 hi = (_Float16)v[t];
            vh[t] = hi;
            vl[t] = (_Float16)(v[t] - (float)hi);
        }
        *(half4*)(oh + e4 * 4) = vh;
        *(half4*)(ol + e4 * 4) = vl;
    }
#pragma unroll
    for (int s = 1; s < 64; s <<= 1) vsum += __shfl_xor(vsum, s, 64);
    if (lane == 0) v_out[row] = vsum;
}

// ---------------- GT = Wk @ Wq^T (GT[c][d] = dot(Wk[c][:], Wq[d][:])), f16x2 3-pass
// Output stored [c][d] row-major == the B^T operand for the t-GEMM.
__global__ __launch_bounds__(256) void gt_kernel(
    const _Float16* __restrict__ wk_hi, const _Float16* __restrict__ wk_lo,
    const _Float16* __restrict__ wq_hi, const _Float16* __restrict__ wq_lo,
    _Float16* __restrict__ gt_hi, _Float16* __restrict__ gt_lo)
{
    __shared__ __attribute__((aligned(16))) _Float16 Ah_s[BM * BK];
    __shared__ __attribute__((aligned(16))) _Float16 Al_s[BM * BK];
    __shared__ __attribute__((aligned(16))) _Float16 Bh_s[BN * BK];
    __shared__ __attribute__((aligned(16))) _Float16 Bl_s[BN * BK];

    int rowbase = blockIdx.y * BM;
    int colbase = blockIdx.x * BN;
    int tid  = threadIdx.x;
    int lane = tid & 63, wave = tid >> 6;
    int wrow = (wave >> 1) * 64, wcol = (wave & 1) * 64;

    floatx4 acc[4][4];
#pragma unroll
    for (int i = 0; i < 4; i++)
#pragma unroll
        for (int j = 0; j < 4; j++) acc[i][j] = (floatx4){0.f, 0.f, 0.f, 0.f};

    size_t arow = (size_t)(rowbase + tid / 4) * EMB;
    size_t brow = (size_t)(colbase + tid / 4) * EMB;
    int    boff = (tid % 4) * 16;
    const char* gAh = (const char*)(wk_hi + arow) + boff;
    const char* gAl = (const char*)(wk_lo + arow) + boff;
    const char* gBh = (const char*)(wq_hi + brow) + boff;
    const char* gBl = (const char*)(wq_lo + brow) + boff;
    char* lAh = (char*)Ah_s + tid * 16;
    char* lAl = (char*)Al_s + tid * 16;
    char* lBh = (char*)Bh_s + tid * 16;
    char* lBl = (char*)Bl_s + tid * 16;
    const size_t half_stride = (size_t)64 * EMB * 2;

    for (int k0 = 0; k0 < EMB; k0 += BK) {
        __syncthreads();
        g2l16(gAh, lAh); g2l16(gAh + half_stride, lAh + 4096);
        g2l16(gAl, lAl); g2l16(gAl + half_stride, lAl + 4096);
        g2l16(gBh, lBh); g2l16(gBh + half_stride, lBh + 4096);
        g2l16(gBl, lBl); g2l16(gBl + half_stride, lBl + 4096);
        gAh += 64; gAl += 64; gBh += 64; gBl += 64;
        __syncthreads();

        half8 ah[4], al[4], bh[4], bl[4];
#pragma unroll
        for (int i = 0; i < 4; i++) {
            int off = (wrow + i * 16 + (lane & 15)) * 64 + (lane >> 4) * 16;
            ah[i] = *(const half8*)((const char*)Ah_s + off);
            al[i] = *(const half8*)((const char*)Al_s + off);
        }
#pragma unroll
        for (int j = 0; j < 4; j++) {
            int off = (wcol + j * 16 + (lane & 15)) * 64 + (lane >> 4) * 16;
            bh[j] = *(const half8*)((const char*)Bh_s + off);
            bl[j] = *(const half8*)((const char*)Bl_s + off);
        }
#pragma unroll
        for (int i = 0; i < 4; i++)
#pragma unroll
            for (int j = 0; j < 4; j++) {
                acc[i][j] = __builtin_amdgcn_mfma_f32_16x16x32_f16(ah[i], bh[j], acc[i][j], 0, 0, 0);
                acc[i][j] = __builtin_amdgcn_mfma_f32_16x16x32_f16(ah[i], bl[j], acc[i][j], 0, 0, 0);
                acc[i][j] = __builtin_amdgcn_mfma_f32_16x16x32_f16(al[i], bh[j], acc[i][j], 0, 0, 0);
            }
    }

#pragma unroll
    for (int j = 0; j < 4; j++) {
        int col = colbase + wcol + j * 16 + (lane & 15);
#pragma unroll
        for (int i = 0; i < 4; i++) {
#pragma unroll
            for (int r = 0; r < 4; r++) {
                int row = rowbase + wrow + i * 16 + (lane >> 4) * 4 + r;
                float v = acc[i][j][r];
                _Float16 hi = (_Float16)v;
                gt_hi[(size_t)row * EMB + col] = hi;
                gt_lo[(size_t)row * EMB + col] = (_Float16)(v - (float)hi);
            }
        }
    }
}

// ---------------- t = hn @ G  (B^T = GT planes), f16x2 3-pass, split epilogue ----
__global__ __launch_bounds__(256) void t_kernel(
    const _Float16* __restrict__ hn_hi, const _Float16* __restrict__ hn_lo,
    const _Float16* __restrict__ gt_hi, const _Float16* __restrict__ gt_lo,
    _Float16* __restrict__ t_hi, _Float16* __restrict__ t_lo)
{
    __shared__ __attribute__((aligned(16))) _Float16 Ah_s[BM * BK];
    __shared__ __attribute__((aligned(16))) _Float16 Al_s[BM * BK];
    __shared__ __attribute__((aligned(16))) _Float16 Bh_s[BN * BK];
    __shared__ __attribute__((aligned(16))) _Float16 Bl_s[BN * BK];

    int rowbase = blockIdx.y * BM;
    int colbase = blockIdx.x * BN;
    int tid  = threadIdx.x;
    int lane = tid & 63, wave = tid >> 6;
    int wrow = (wave >> 1) * 64, wcol = (wave & 1) * 64;

    floatx4 acc[4][4];
#pragma unroll
    for (int i = 0; i < 4; i++)
#pragma unroll
        for (int j = 0; j < 4; j++) acc[i][j] = (floatx4){0.f, 0.f, 0.f, 0.f};

    size_t arow = (size_t)(rowbase + tid / 4) * EMB;
    size_t brow = (size_t)(colbase + tid / 4) * EMB;
    int    boff = (tid % 4) * 16;
    const char* gAh = (const char*)(hn_hi + arow) + boff;
    const char* gAl = (const char*)(hn_lo + arow) + boff;
    const char* gBh = (const char*)(gt_hi + brow) + boff;
    const char* gBl = (const char*)(gt_lo + brow) + boff;
    char* lAh = (char*)Ah_s + tid * 16;
    char* lAl = (char*)Al_s + tid * 16;
    char* lBh = (char*)Bh_s + tid * 16;
    char* lBl = (char*)Bl_s + tid * 16;
    const size_t half_stride = (size_t)64 * EMB * 2;

    for (int k0 = 0; k0 < EMB; k0 += BK) {
        __syncthreads();
        g2l16(gAh, lAh); g2l16(gAh + half_stride, lAh + 4096);
        g2l16(gAl, lAl); g2l16(gAl + half_stride, lAl + 4096);
        g2l16(gBh, lBh); g2l16(gBh + half_stride, lBh + 4096);
        g2l16(gBl, lBl); g2l16(gBl + half_stride, lBl + 4096);
        gAh += 64; gAl += 64; gBh += 64; gBl += 64;
        __syncthreads();

        half8 ah[4], al[4], bh[4], bl[4];
#pragma unroll
        for (int i = 0; i < 4; i++) {
            int off = (wrow + i * 16 + (lane & 15)) * 64 + (lane >> 4) * 16;
            ah[i] = *(const half8*)((const char*)Ah_s + off);
            al[i] = *(const half8*)((const char*)Al_s + off);
        }
#pragma unroll
        for (int j = 0; j < 4; j++) {
            int off = (wcol + j * 16 + (lane & 15)) * 64 + (lane >> 4) * 16;
            bh[j] = *(const half8*)((const char*)Bh_s + off);
            bl[j] = *(const half8*)((const char*)Bl_s + off);
        }
#pragma unroll
        for (int i = 0; i < 4; i++)
#pragma unroll
            for (int j = 0; j < 4; j++) {
                acc[i][j] = __builtin_amdgcn_mfma_f32_16x16x32_f16(ah[i], bh[j], acc[i][j], 0, 0, 0);
                acc[i][j] = __builtin_amdgcn_mfma_f32_16x16x32_f16(ah[i], bl[j], acc[i][j], 0, 0, 0);
                acc[i][j] = __builtin_amdgcn_mfma_f32_16x16x32_f16(al[i], bh[j], acc[i][j], 0, 0, 0);
            }
    }

#pragma unroll
    for (int j = 0; j < 4; j++) {
        int col = colbase + wcol + j * 16 + (lane & 15);
#pragma unroll
        for (int i = 0; i < 4; i++) {
#pragma unroll
            for (int r = 0; r < 4; r++) {
                int row = rowbase + wrow + i * 16 + (lane >> 4) * 4 + r;
                float v = acc[i][j][r];
                _Float16 hi = (_Float16)v;
                t_hi[(size_t)row * EMB + col] = hi;
                t_lo[(size_t)row * EMB + col] = (_Float16)(v - (float)hi);
            }
        }
    }
}

// ---------------- scores: s = t @ hn^T + v_c, 2-pass (th*hh + th*hl) + softmax partial
__global__ __launch_bounds__(256) void scores_kernel(
    const _Float16* __restrict__ t_hi,
    const _Float16* __restrict__ hn_hi, const _Float16* __restrict__ hn_lo,
    const float* __restrict__ v_in,
    float* __restrict__ out,
    float2* __restrict__ state)
{
    __shared__ __attribute__((aligned(16))) _Float16 Ah_s[BM * BK];
    __shared__ __attribute__((aligned(16))) _Float16 Bh_s[BN * BK];
    __shared__ __attribute__((aligned(16))) _Float16 Bl_s[BN * BK];
    __shared__ float red[128][2];

    int b = blockIdx.z;
    size_t base = (size_t)b * SEQ * EMB;
    int rowbase = blockIdx.y * BM;
    int colbase = blockIdx.x * BN;
    int tid  = threadIdx.x;
    int lane = tid & 63, wave = tid >> 6;
    int wrow = (wave >> 1) * 64, wcol = (wave & 1) * 64;

    floatx4 acc[4][4];
#pragma unroll
    for (int i = 0; i < 4; i++)
#pragma unroll
        for (int j = 0; j < 4; j++) acc[i][j] = (floatx4){0.f, 0.f, 0.f, 0.f};

    size_t arow = base + (size_t)(rowbase + tid / 4) * EMB;
    size_t brow = base + (size_t)(colbase + tid / 4) * EMB;
    int    boff = (tid % 4) * 16;
    const char* gAh = (const char*)(t_hi + arow) + boff;
    const char* gBh = (const char*)(hn_hi + brow) + boff;
    const char* gBl = (const char*)(hn_lo + brow) + boff;
    char* lAh = (char*)Ah_s + tid * 16;
    char* lBh = (char*)Bh_s + tid * 16;
    char* lBl = (char*)Bl_s + tid * 16;
    const size_t half_stride = (size_t)64 * EMB * 2;

    for (int k0 = 0; k0 < EMB; k0 += BK) {
        __syncthreads();
        g2l16(gAh, lAh); g2l16(gAh + half_stride, lAh + 4096);
        g2l16(gBh, lBh); g2l16(gBh + half_stride, lBh + 4096);
        g2l16(gBl, lBl); g2l16(gBl + half_stride, lBl + 4096);
        gAh += 64; gBh += 64; gBl += 64;
        __syncthreads();

        half8 ah[4], bh[4], bl[4];
#pragma unroll
        for (int i = 0; i < 4; i++) {
            int off = (wrow + i * 16 + (lane & 15)) * 64 + (lane >> 4) * 16;
            ah[i] = *(const half8*)((const char*)Ah_s + off);
        }
#pragma unroll
        for (int j = 0; j < 4; j++) {
            int off = (wcol + j * 16 + (lane & 15)) * 64 + (lane >> 4) * 16;
            bh[j] = *(const half8*)((const char*)Bh_s + off);
            bl[j] = *(const half8*)((const char*)Bl_s + off);
        }
#pragma unroll
        for (int i = 0; i < 4; i++)
#pragma unroll
            for (int j = 0; j < 4; j++) {
                acc[i][j] = __builtin_amdgcn_mfma_f32_16x16x32_f16(ah[i], bh[j], acc[i][j], 0, 0, 0);
                acc[i][j] = __builtin_amdgcn_mfma_f32_16x16x32_f16(ah[i], bl[j], acc[i][j], 0, 0, 0);
            }
    }

    // add column term v_c
    const float* vb = v_in + (size_t)b * SEQ + colbase;
#pragma unroll
    for (int j = 0; j < 4; j++) {
        float vv = vb[wcol + j * 16 + (lane & 15)];
#pragma unroll
        for (int i = 0; i < 4; i++)
#pragma unroll
            for (int r = 0; r < 4; r++) acc[i][j][r] += vv;
    }

    // ---- softmax partial epilogue ----
    float m1[4][4];
#pragma unroll
    for (int i = 0; i < 4; i++)
#pragma unroll
        for (int r = 0; r < 4; r++) {
            float m = fmaxf(fmaxf(acc[i][0][r], acc[i][1][r]), fmaxf(acc[i][2][r], acc[i][3][r]));
#pragma unroll
            for (int s = 1; s < 16; s <<= 1) m = fmaxf(m, __shfl_xor(m, s, 64));
            m1[i][r] = m;
        }
    if ((lane & 15) == 0) {
#pragma unroll
        for (int i = 0; i < 4; i++)
#pragma unroll
            for (int r = 0; r < 4; r++)
                red[wrow + i * 16 + (lane >> 4) * 4 + r][wave & 1] = m1[i][r];
    }
    __syncthreads();
    float mrow[4][4];
#pragma unroll
    for (int i = 0; i < 4; i++)
#pragma unroll
        for (int r = 0; r < 4; r++) {
            int rr = wrow + i * 16 + (lane >> 4) * 4 + r;
            mrow[i][r] = fmaxf(red[rr][0], red[rr][1]);
        }
    __syncthreads();

    float ls[4][4];
#pragma unroll
    for (int i = 0; i < 4; i++)
#pragma unroll
        for (int r = 0; r < 4; r++) {
            float s = 0.f;
#pragma unroll
            for (int j = 0; j < 4; j++) {
                float e = __expf(acc[i][j][r] - mrow[i][r]);
                acc[i][j][r] = e;
                s += e;
            }
#pragma unroll
            for (int sh = 1; sh < 16; sh <<= 1) s += __shfl_xor(s, sh, 64);
            ls[i][r] = s;
        }
    if ((lane & 15) == 0) {
#pragma unroll
        for (int i = 0; i < 4; i++)
#pragma unroll
            for (int r = 0; r < 4; r++)
                red[wrow + i * 16 + (lane >> 4) * 4 + r][wave & 1] = ls[i][r];
    }
    __syncthreads();

    // write ptilde (f32)
    size_t outbase = (size_t)b * SEQ * SEQ;
#pragma unroll
    for (int i = 0; i < 4; i++)
#pragma unroll
        for (int j = 0; j < 4; j++)
#pragma unroll
            for (int r = 0; r < 4; r++) {
                int row = rowbase + wrow + i * 16 + (lane >> 4) * 4 + r;
                int col = colbase + wcol + j * 16 + (lane & 15);
                out[outbase + (size_t)row * SEQ + col] = acc[i][j][r];
            }

    // write per-(row, colblock) state
    if ((wave & 1) == 0 && (lane & 15) == 0) {
#pragma unroll
        for (int i = 0; i < 4; i++)
#pragma unroll
            for (int r = 0; r < 4; r++) {
                int rr = wrow + i * 16 + (lane >> 4) * 4 + r;     // local row
                float l = red[rr][0] + red[rr][1];
                state[((size_t)b * SEQ + rowbase + rr) * 16 + blockIdx.x] =
                    make_float2(mrow[i][r], l);
            }
    }
}

// ---------------- fixup: global softmax normalize ----------------
__global__ __launch_bounds__(256) void fixup_kernel(
    float* __restrict__ out,
    const float2* __restrict__ state)
{
    int row  = blockIdx.x * 4 + (threadIdx.x >> 6);
    int lane = threadIdx.x & 63;
    const float2* st = state + (size_t)row * 16;
    float m[16], l[16];
    float M = -INFINITY;
#pragma unroll
    for (int t = 0; t < 16; t++) { float2 v = st[t]; m[t] = v.x; l[t] = v.y; M = fmaxf(M, m[t]); }
    float L = 0.f;
#pragma unroll
    for (int t = 0; t < 16; t++) { m[t] = __expf(m[t] - M); L += l[t] * m[t]; }
    float inv = 1.0f / L;
    float4* o4 = (float4*)(out + (size_t)row * SEQ);
#pragma unroll
    for (int c0 = 0; c0 < 8; c0++) {
        int i4 = c0 * 64 + lane;            // float4 index; element = i4*4
        float s = m[i4 >> 5] * inv;         // (i4*4)>>7 == i4>>5
        float4 v = o4[i4];
        v.x *= s; v.y *= s; v.z *= s; v.w *= s;
        o4[i4] = v;
    }
}

extern "C" void kernel_launch(void* const* d_in, const int* in_sizes, int n_in,
                              void* d_out, int out_size, void* d_ws, size_t ws_size,
                              hipStream_t stream)
{
    const float* h  = (const float*)d_in[0];
    const float* g  = (const float*)d_in[1];
    const float* be = (const float*)d_in[2];
    const float* wq = (const float*)d_in[3];
    const float* bq = (const float*)d_in[4];
    const float* wk = (const float*)d_in[5];
    const float* bk = (const float*)d_in[6];
    (void)bk;  // bk contributes only softmax-invariant row/const terms
    float* out = (float*)d_out;

    char* ws = (char*)d_ws;
    const size_t SZ  = (size_t)ROWS * EMB * 2;         // 25,165,824 B per 16384x768 f16 plane
    const size_t WSZ = (size_t)EMB * EMB * 2;          // 1,179,648 B per 768x768 f16 plane
    _Float16* hn_hi = (_Float16*)(ws);
    _Float16* hn_lo = (_Float16*)(ws + SZ);
    _Float16* t_hi  = (_Float16*)(ws + 2 * SZ);
    _Float16* t_lo  = (_Float16*)(ws + 3 * SZ);
    char* wbase = ws + 4 * SZ;
    _Float16* wq_hi = (_Float16*)(wbase);
    _Float16* wq_lo = (_Float16*)(wbase + WSZ);
    _Float16* wk_hi = (_Float16*)(wbase + 2 * WSZ);
    _Float16* wk_lo = (_Float16*)(wbase + 3 * WSZ);
    _Float16* gt_hi = (_Float16*)(wbase + 4 * WSZ);
    _Float16* gt_lo = (_Float16*)(wbase + 5 * WSZ);
    char* sbase = wbase + 6 * WSZ;
    float*  wt = (float*)(sbase);                      // 768 f32
    float*  v  = (float*)(sbase + 4096);               // 16384 f32
    float2* st = (float2*)(sbase + 4096 + 65536);      // 2 MB

    split_w_kernel<<<dim3(576, 2), 256, 0, stream>>>(wq, wk, wq_hi, wq_lo, wk_hi, wk_lo);
    wtilde_kernel<<<dim3(EMB / 4), 256, 0, stream>>>(wk, bq, wt);
    ln_kernel<<<dim3(ROWS / 4), 256, 0, stream>>>(h, g, be, wt, hn_hi, hn_lo, v);
    gt_kernel<<<dim3(EMB / BN, EMB / BM), 256, 0, stream>>>(wk_hi, wk_lo, wq_hi, wq_lo, gt_hi, gt_lo);
    t_kernel<<<dim3(EMB / BN, ROWS / BM), 256, 0, stream>>>(hn_hi, hn_lo, gt_hi, gt_lo, t_hi, t_lo);
    scores_kernel<<<dim3(SEQ / BN, SEQ / BM, BATCH), 256, 0, stream>>>(t_hi, hn_hi, hn_lo, v, out, st);
    fixup_kernel<<<dim3(ROWS / 4), 256, 0, stream>>>(out, st);
}

// Round 5
// 393.591 us; speedup vs baseline: 1.3899x; 1.1973x over previous
//
#include <hip/hip_runtime.h>
#include <stdint.h>

#define EMB   768
#define BATCH 8
#define SEQ   2048
#define ROWS  (BATCH*SEQ)     // 16384
#define EPS   1e-5f

#define BM 128
#define BN 128
#define BK 32

typedef _Float16 half8 __attribute__((ext_vector_type(8)));
typedef _Float16 half4 __attribute__((ext_vector_type(4)));
typedef float    floatx4 __attribute__((ext_vector_type(4)));

// async global->LDS, 16B per lane (global_load_lds_dwordx4).
__device__ __forceinline__ void g2l16(const void* g, void* l) {
    __builtin_amdgcn_global_load_lds(
        (const __attribute__((address_space(1))) unsigned int*)g,
        (__attribute__((address_space(3))) unsigned int*)l,
        16, 0, 0);
}

// ---------------- split weights: f32 -> f16 hi/lo planes ----------------
__global__ __launch_bounds__(256) void split_w_kernel(
    const float* __restrict__ wq, const float* __restrict__ wk,
    _Float16* __restrict__ wq_hi, _Float16* __restrict__ wq_lo,
    _Float16* __restrict__ wk_hi, _Float16* __restrict__ wk_lo)
{
    const float* src = (blockIdx.y == 0) ? wq : wk;
    _Float16* dh     = (blockIdx.y == 0) ? wq_hi : wk_hi;
    _Float16* dl     = (blockIdx.y == 0) ? wq_lo : wk_lo;
    int i4 = blockIdx.x * 256 + threadIdx.x;
    float4 v = ((const float4*)src)[i4];
    half4 vh, vl;
    float c[4] = {v.x, v.y, v.z, v.w};
#pragma unroll
    for (int t = 0; t < 4; t++) {
        _Float16 hi = (_Float16)c[t];
        vh[t] = hi;
        vl[t] = (_Float16)(c[t] - (float)hi);
    }
    ((half4*)dh)[i4] = vh;
    ((half4*)dl)[i4] = vl;
}

// ---------------- wtilde = Wk @ bq ----------------
__global__ __launch_bounds__(256) void wtilde_kernel(
    const float* __restrict__ wk, const float* __restrict__ bq,
    float* __restrict__ wt)
{
    int row  = blockIdx.x * 4 + (threadIdx.x >> 6);
    int lane = threadIdx.x & 63;
    const float4* r4 = (const float4*)(wk + (size_t)row * EMB);
    const float4* b4 = (const float4*)bq;
    float s = 0.f;
#pragma unroll
    for (int j = 0; j < 3; j++) {
        float4 a = r4[lane + j * 64];
        float4 b = b4[lane + j * 64];
        s += a.x * b.x + a.y * b.y + a.z * b.z + a.w * b.w;
    }
#pragma unroll
    for (int sh = 1; sh < 64; sh <<= 1) s += __shfl_xor(s, sh, 64);
    if (lane == 0) wt[row] = s;
}

// ---------------- LayerNorm: f32 in -> f16 hi only, + v = hn . wtilde -------
__global__ __launch_bounds__(256) void ln_kernel(
    const float* __restrict__ h,
    const float* __restrict__ gamma,
    const float* __restrict__ beta,
    const float* __restrict__ wt,
    _Float16* __restrict__ hn_hi,
    float* __restrict__ v_out)
{
    int row  = blockIdx.x * 4 + (threadIdx.x >> 6);
    int lane = threadIdx.x & 63;
    const float4* hr4 = (const float4*)(h + (size_t)row * EMB);
    float4 x[3];
    float s1 = 0.f, s2 = 0.f;
#pragma unroll
    for (int j = 0; j < 3; j++) {
        x[j] = hr4[lane + j * 64];
        s1 += x[j].x + x[j].y + x[j].z + x[j].w;
        s2 += x[j].x * x[j].x + x[j].y * x[j].y + x[j].z * x[j].z + x[j].w * x[j].w;
    }
#pragma unroll
    for (int s = 1; s < 64; s <<= 1) {
        s1 += __shfl_xor(s1, s, 64);
        s2 += __shfl_xor(s2, s, 64);
    }
    float mu  = s1 * (1.0f / EMB);
    float var = s2 * (1.0f / EMB) - mu * mu;
    float rs  = rsqrtf(var + EPS);
    _Float16* oh = hn_hi + (size_t)row * EMB;
    float vsum = 0.f;
#pragma unroll
    for (int j = 0; j < 3; j++) {
        int e4 = lane + j * 64;
        float4 g = ((const float4*)gamma)[e4];
        float4 b = ((const float4*)beta)[e4];
        float4 w = ((const float4*)wt)[e4];
        float v[4] = {
            (x[j].x - mu) * rs * g.x + b.x,
            (x[j].y - mu) * rs * g.y + b.y,
            (x[j].z - mu) * rs * g.z + b.z,
            (x[j].w - mu) * rs * g.w + b.w };
        vsum += v[0] * w.x + v[1] * w.y + v[2] * w.z + v[3] * w.w;
        half4 vh;
#pragma unroll
        for (int t = 0; t < 4; t++) vh[t] = (_Float16)v[t];
        *(half4*)(oh + e4 * 4) = vh;
    }
#pragma unroll
    for (int s = 1; s < 64; s <<= 1) vsum += __shfl_xor(vsum, s, 64);
    if (lane == 0) v_out[row] = vsum;
}

// ---------------- GT = Wk @ Wq^T, f16x2 3-pass, hi/lo split output ----------
__global__ __launch_bounds__(256) void gt_kernel(
    const _Float16* __restrict__ wk_hi, const _Float16* __restrict__ wk_lo,
    const _Float16* __restrict__ wq_hi, const _Float16* __restrict__ wq_lo,
    _Float16* __restrict__ gt_hi, _Float16* __restrict__ gt_lo)
{
    __shared__ __attribute__((aligned(16))) _Float16 Ah_s[BM * BK];
    __shared__ __attribute__((aligned(16))) _Float16 Al_s[BM * BK];
    __shared__ __attribute__((aligned(16))) _Float16 Bh_s[BN * BK];
    __shared__ __attribute__((aligned(16))) _Float16 Bl_s[BN * BK];

    int rowbase = blockIdx.y * BM;
    int colbase = blockIdx.x * BN;
    int tid  = threadIdx.x;
    int lane = tid & 63, wave = tid >> 6;
    int wrow = (wave >> 1) * 64, wcol = (wave & 1) * 64;

    floatx4 acc[4][4];
#pragma unroll
    for (int i = 0; i < 4; i++)
#pragma unroll
        for (int j = 0; j < 4; j++) acc[i][j] = (floatx4){0.f, 0.f, 0.f, 0.f};

    size_t arow = (size_t)(rowbase + tid / 4) * EMB;
    size_t brow = (size_t)(colbase + tid / 4) * EMB;
    int    boff = (tid % 4) * 16;
    const char* gAh = (const char*)(wk_hi + arow) + boff;
    const char* gAl = (const char*)(wk_lo + arow) + boff;
    const char* gBh = (const char*)(wq_hi + brow) + boff;
    const char* gBl = (const char*)(wq_lo + brow) + boff;
    char* lAh = (char*)Ah_s + tid * 16;
    char* lAl = (char*)Al_s + tid * 16;
    char* lBh = (char*)Bh_s + tid * 16;
    char* lBl = (char*)Bl_s + tid * 16;
    const size_t half_stride = (size_t)64 * EMB * 2;

    for (int k0 = 0; k0 < EMB; k0 += BK) {
        __syncthreads();
        g2l16(gAh, lAh); g2l16(gAh + half_stride, lAh + 4096);
        g2l16(gAl, lAl); g2l16(gAl + half_stride, lAl + 4096);
        g2l16(gBh, lBh); g2l16(gBh + half_stride, lBh + 4096);
        g2l16(gBl, lBl); g2l16(gBl + half_stride, lBl + 4096);
        gAh += 64; gAl += 64; gBh += 64; gBl += 64;
        __syncthreads();

        half8 ah[4], al[4], bh[4], bl[4];
#pragma unroll
        for (int i = 0; i < 4; i++) {
            int off = (wrow + i * 16 + (lane & 15)) * 64 + (lane >> 4) * 16;
            ah[i] = *(const half8*)((const char*)Ah_s + off);
            al[i] = *(const half8*)((const char*)Al_s + off);
        }
#pragma unroll
        for (int j = 0; j < 4; j++) {
            int off = (wcol + j * 16 + (lane & 15)) * 64 + (lane >> 4) * 16;
            bh[j] = *(const half8*)((const char*)Bh_s + off);
            bl[j] = *(const half8*)((const char*)Bl_s + off);
        }
#pragma unroll
        for (int i = 0; i < 4; i++)
#pragma unroll
            for (int j = 0; j < 4; j++) {
                acc[i][j] = __builtin_amdgcn_mfma_f32_16x16x32_f16(ah[i], bh[j], acc[i][j], 0, 0, 0);
                acc[i][j] = __builtin_amdgcn_mfma_f32_16x16x32_f16(ah[i], bl[j], acc[i][j], 0, 0, 0);
                acc[i][j] = __builtin_amdgcn_mfma_f32_16x16x32_f16(al[i], bh[j], acc[i][j], 0, 0, 0);
            }
    }

#pragma unroll
    for (int j = 0; j < 4; j++) {
        int col = colbase + wcol + j * 16 + (lane & 15);
#pragma unroll
        for (int i = 0; i < 4; i++) {
#pragma unroll
            for (int r = 0; r < 4; r++) {
                int row = rowbase + wrow + i * 16 + (lane >> 4) * 4 + r;
                float v = acc[i][j][r];
                _Float16 hi = (_Float16)v;
                gt_hi[(size_t)row * EMB + col] = hi;
                gt_lo[(size_t)row * EMB + col] = (_Float16)(v - (float)hi);
            }
        }
    }
}

// ---------------- t = hn_hi @ G  (2-pass: ah*gh + ah*gl), t_hi only ----------
__global__ __launch_bounds__(256) void t_kernel(
    const _Float16* __restrict__ hn_hi,
    const _Float16* __restrict__ gt_hi, const _Float16* __restrict__ gt_lo,
    _Float16* __restrict__ t_hi)
{
    __shared__ __attribute__((aligned(16))) _Float16 Ah_s[BM * BK];
    __shared__ __attribute__((aligned(16))) _Float16 Bh_s[BN * BK];
    __shared__ __attribute__((aligned(16))) _Float16 Bl_s[BN * BK];

    int rowbase = blockIdx.y * BM;
    int colbase = blockIdx.x * BN;
    int tid  = threadIdx.x;
    int lane = tid & 63, wave = tid >> 6;
    int wrow = (wave >> 1) * 64, wcol = (wave & 1) * 64;

    floatx4 acc[4][4];
#pragma unroll
    for (int i = 0; i < 4; i++)
#pragma unroll
        for (int j = 0; j < 4; j++) acc[i][j] = (floatx4){0.f, 0.f, 0.f, 0.f};

    size_t arow = (size_t)(rowbase + tid / 4) * EMB;
    size_t brow = (size_t)(colbase + tid / 4) * EMB;
    int    boff = (tid % 4) * 16;
    const char* gAh = (const char*)(hn_hi + arow) + boff;
    const char* gBh = (const char*)(gt_hi + brow) + boff;
    const char* gBl = (const char*)(gt_lo + brow) + boff;
    char* lAh = (char*)Ah_s + tid * 16;
    char* lBh = (char*)Bh_s + tid * 16;
    char* lBl = (char*)Bl_s + tid * 16;
    const size_t half_stride = (size_t)64 * EMB * 2;

    for (int k0 = 0; k0 < EMB; k0 += BK) {
        __syncthreads();
        g2l16(gAh, lAh); g2l16(gAh + half_stride, lAh + 4096);
        g2l16(gBh, lBh); g2l16(gBh + half_stride, lBh + 4096);
        g2l16(gBl, lBl); g2l16(gBl + half_stride, lBl + 4096);
        gAh += 64; gBh += 64; gBl += 64;
        __syncthreads();

        half8 ah[4], bh[4], bl[4];
#pragma unroll
        for (int i = 0; i < 4; i++) {
            int off = (wrow + i * 16 + (lane & 15)) * 64 + (lane >> 4) * 16;
            ah[i] = *(const half8*)((const char*)Ah_s + off);
        }
#pragma unroll
        for (int j = 0; j < 4; j++) {
            int off = (wcol + j * 16 + (lane & 15)) * 64 + (lane >> 4) * 16;
            bh[j] = *(const half8*)((const char*)Bh_s + off);
            bl[j] = *(const half8*)((const char*)Bl_s + off);
        }
#pragma unroll
        for (int i = 0; i < 4; i++)
#pragma unroll
            for (int j = 0; j < 4; j++) {
                acc[i][j] = __builtin_amdgcn_mfma_f32_16x16x32_f16(ah[i], bh[j], acc[i][j], 0, 0, 0);
                acc[i][j] = __builtin_amdgcn_mfma_f32_16x16x32_f16(ah[i], bl[j], acc[i][j], 0, 0, 0);
            }
    }

#pragma unroll
    for (int j = 0; j < 4; j++) {
        int col = colbase + wcol + j * 16 + (lane & 15);
#pragma unroll
        for (int i = 0; i < 4; i++) {
#pragma unroll
            for (int r = 0; r < 4; r++) {
                int row = rowbase + wrow + i * 16 + (lane >> 4) * 4 + r;
                t_hi[(size_t)row * EMB + col] = (_Float16)acc[i][j][r];
            }
        }
    }
}

// ---------------- scores: s = t_hi @ hn_hi^T + v_c, 1-pass + softmax partial --
__global__ __launch_bounds__(256) void scores_kernel(
    const _Float16* __restrict__ t_hi,
    const _Float16* __restrict__ hn_hi,
    const float* __restrict__ v_in,
    float* __restrict__ out,
    float2* __restrict__ state)
{
    __shared__ __attribute__((aligned(16))) _Float16 Ah_s[BM * BK];
    __shared__ __attribute__((aligned(16))) _Float16 Bh_s[BN * BK];
    __shared__ float red[128][2];

    int b = blockIdx.z;
    size_t base = (size_t)b * SEQ * EMB;
    int rowbase = blockIdx.y * BM;
    int colbase = blockIdx.x * BN;
    int tid  = threadIdx.x;
    int lane = tid & 63, wave = tid >> 6;
    int wrow = (wave >> 1) * 64, wcol = (wave & 1) * 64;

    floatx4 acc[4][4];
#pragma unroll
    for (int i = 0; i < 4; i++)
#pragma unroll
        for (int j = 0; j < 4; j++) acc[i][j] = (floatx4){0.f, 0.f, 0.f, 0.f};

    size_t arow = base + (size_t)(rowbase + tid / 4) * EMB;
    size_t brow = base + (size_t)(colbase + tid / 4) * EMB;
    int    boff = (tid % 4) * 16;
    const char* gAh = (const char*)(t_hi + arow) + boff;
    const char* gBh = (const char*)(hn_hi + brow) + boff;
    char* lAh = (char*)Ah_s + tid * 16;
    char* lBh = (char*)Bh_s + tid * 16;
    const size_t half_stride = (size_t)64 * EMB * 2;

    for (int k0 = 0; k0 < EMB; k0 += BK) {
        __syncthreads();
        g2l16(gAh, lAh); g2l16(gAh + half_stride, lAh + 4096);
        g2l16(gBh, lBh); g2l16(gBh + half_stride, lBh + 4096);
        gAh += 64; gBh += 64;
        __syncthreads();

        half8 ah[4], bh[4];
#pragma unroll
        for (int i = 0; i < 4; i++) {
            int off = (wrow + i * 16 + (lane & 15)) * 64 + (lane >> 4) * 16;
            ah[i] = *(const half8*)((const char*)Ah_s + off);
        }
#pragma unroll
        for (int j = 0; j < 4; j++) {
            int off = (wcol + j * 16 + (lane & 15)) * 64 + (lane >> 4) * 16;
            bh[j] = *(const half8*)((const char*)Bh_s + off);
        }
#pragma unroll
        for (int i = 0; i < 4; i++)
#pragma unroll
            for (int j = 0; j < 4; j++)
                acc[i][j] = __builtin_amdgcn_mfma_f32_16x16x32_f16(ah[i], bh[j], acc[i][j], 0, 0, 0);
    }

    // add column term v_c
    const float* vb = v_in + (size_t)b * SEQ + colbase;
#pragma unroll
    for (int j = 0; j < 4; j++) {
        float vv = vb[wcol + j * 16 + (lane & 15)];
#pragma unroll
        for (int i = 0; i < 4; i++)
#pragma unroll
            for (int r = 0; r < 4; r++) acc[i][j][r] += vv;
    }

    // ---- softmax partial epilogue ----
    float m1[4][4];
#pragma unroll
    for (int i = 0; i < 4; i++)
#pragma unroll
        for (int r = 0; r < 4; r++) {
            float m = fmaxf(fmaxf(acc[i][0][r], acc[i][1][r]), fmaxf(acc[i][2][r], acc[i][3][r]));
#pragma unroll
            for (int s = 1; s < 16; s <<= 1) m = fmaxf(m, __shfl_xor(m, s, 64));
            m1[i][r] = m;
        }
    if ((lane & 15) == 0) {
#pragma unroll
        for (int i = 0; i < 4; i++)
#pragma unroll
            for (int r = 0; r < 4; r++)
                red[wrow + i * 16 + (lane >> 4) * 4 + r][wave & 1] = m1[i][r];
    }
    __syncthreads();
    float mrow[4][4];
#pragma unroll
    for (int i = 0; i < 4; i++)
#pragma unroll
        for (int r = 0; r < 4; r++) {
            int rr = wrow + i * 16 + (lane >> 4) * 4 + r;
            mrow[i][r] = fmaxf(red[rr][0], red[rr][1]);
        }
    __syncthreads();

    float ls[4][4];
#pragma unroll
    for (int i = 0; i < 4; i++)
#pragma unroll
        for (int r = 0; r < 4; r++) {
            float s = 0.f;
#pragma unroll
            for (int j = 0; j < 4; j++) {
                float e = __expf(acc[i][j][r] - mrow[i][r]);
                acc[i][j][r] = e;
                s += e;
            }
#pragma unroll
            for (int sh = 1; sh < 16; sh <<= 1) s += __shfl_xor(s, sh, 64);
            ls[i][r] = s;
        }
    if ((lane & 15) == 0) {
#pragma unroll
        for (int i = 0; i < 4; i++)
#pragma unroll
            for (int r = 0; r < 4; r++)
                red[wrow + i * 16 + (lane >> 4) * 4 + r][wave & 1] = ls[i][r];
    }
    __syncthreads();

    // write ptilde (f32)
    size_t outbase = (size_t)b * SEQ * SEQ;
#pragma unroll
    for (int i = 0; i < 4; i++)
#pragma unroll
        for (int j = 0; j < 4; j++)
#pragma unroll
            for (int r = 0; r < 4; r++) {
                int row = rowbase + wrow + i * 16 + (lane >> 4) * 4 + r;
                int col = colbase + wcol + j * 16 + (lane & 15);
                out[outbase + (size_t)row * SEQ + col] = acc[i][j][r];
            }

    // write per-(row, colblock) state
    if ((wave & 1) == 0 && (lane & 15) == 0) {
#pragma unroll
        for (int i = 0; i < 4; i++)
#pragma unroll
            for (int r = 0; r < 4; r++) {
                int rr = wrow + i * 16 + (lane >> 4) * 4 + r;
                float l = red[rr][0] + red[rr][1];
                state[((size_t)b * SEQ + rowbase + rr) * 16 + blockIdx.x] =
                    make_float2(mrow[i][r], l);
            }
    }
}

// ---------------- fixup: global softmax normalize ----------------
__global__ __launch_bounds__(256) void fixup_kernel(
    float* __restrict__ out,
    const float2* __restrict__ state)
{
    int row  = blockIdx.x * 4 + (threadIdx.x >> 6);
    int lane = threadIdx.x & 63;
    const float2* st = state + (size_t)row * 16;
    float m[16], l[16];
    float M = -INFINITY;
#pragma unroll
    for (int t = 0; t < 16; t++) { float2 v = st[t]; m[t] = v.x; l[t] = v.y; M = fmaxf(M, m[t]); }
    float L = 0.f;
#pragma unroll
    for (int t = 0; t < 16; t++) { m[t] = __expf(m[t] - M); L += l[t] * m[t]; }
    float inv = 1.0f / L;
    float4* o4 = (float4*)(out + (size_t)row * SEQ);
#pragma unroll
    for (int c0 = 0; c0 < 8; c0++) {
        int i4 = c0 * 64 + lane;
        float s = m[i4 >> 5] * inv;
        float4 v = o4[i4];
        v.x *= s; v.y *= s; v.z *= s; v.w *= s;
        o4[i4] = v;
    }
}

extern "C" void kernel_launch(void* const* d_in, const int* in_sizes, int n_in,
                              void* d_out, int out_size, void* d_ws, size_t ws_size,
                              hipStream_t stream)
{
    const float* h  = (const float*)d_in[0];
    const float* g  = (const float*)d_in[1];
    const float* be = (const float*)d_in[2];
    const float* wq = (const float*)d_in[3];
    const float* bq = (const float*)d_in[4];
    const float* wk = (const float*)d_in[5];
    const float* bk = (const float*)d_in[6];
    (void)bk;  // bk contributes only softmax-invariant row/const terms
    float* out = (float*)d_out;

    char* ws = (char*)d_ws;
    const size_t SZ  = (size_t)ROWS * EMB * 2;         // 25,165,824 B per 16384x768 f16 plane
    const size_t WSZ = (size_t)EMB * EMB * 2;          // 1,179,648 B per 768x768 f16 plane
    _Float16* hn_hi = (_Float16*)(ws);
    _Float16* t_hi  = (_Float16*)(ws + SZ);
    char* wbase = ws + 2 * SZ;
    _Float16* wq_hi = (_Float16*)(wbase);
    _Float16* wq_lo = (_Float16*)(wbase + WSZ);
    _Float16* wk_hi = (_Float16*)(wbase + 2 * WSZ);
    _Float16* wk_lo = (_Float16*)(wbase + 3 * WSZ);
    _Float16* gt_hi = (_Float16*)(wbase + 4 * WSZ);
    _Float16* gt_lo = (_Float16*)(wbase + 5 * WSZ);
    char* sbase = wbase + 6 * WSZ;
    float*  wt = (float*)(sbase);                      // 768 f32
    float*  v  = (float*)(sbase + 4096);               // 16384 f32
    float2* st = (float2*)(sbase + 4096 + 65536);      // 2 MB

    split_w_kernel<<<dim3(576, 2), 256, 0, stream>>>(wq, wk, wq_hi, wq_lo, wk_hi, wk_lo);
    wtilde_kernel<<<dim3(EMB / 4), 256, 0, stream>>>(wk, bq, wt);
    ln_kernel<<<dim3(ROWS / 4), 256, 0, stream>>>(h, g, be, wt, hn_hi, v);
    gt_kernel<<<dim3(EMB / BN, EMB / BM), 256, 0, stream>>>(wk_hi, wk_lo, wq_hi, wq_lo, gt_hi, gt_lo);
    t_kernel<<<dim3(EMB / BN, ROWS / BM), 256, 0, stream>>>(hn_hi, gt_hi, gt_lo, t_hi);
    scores_kernel<<<dim3(SEQ / BN, SEQ / BM, BATCH), 256, 0, stream>>>(t_hi, hn_hi, v, out, st);
    fixup_kernel<<<dim3(ROWS / 4), 256, 0, stream>>>(out, st);
}

// Round 6
// 391.957 us; speedup vs baseline: 1.3957x; 1.0042x over previous
//
#include <hip/hip_runtime.h>
#include <stdint.h>

#define EMB   768
#define BATCH 8
#define SEQ   2048
#define ROWS  (BATCH*SEQ)     // 16384
#define EPS   1e-5f

#define BM 128
#define BN 128
#define BK 32
#define BK2 64

typedef _Float16 half8 __attribute__((ext_vector_type(8)));
typedef _Float16 half4 __attribute__((ext_vector_type(4)));
typedef float    floatx4 __attribute__((ext_vector_type(4)));

// async global->LDS, 16B per lane (global_load_lds_dwordx4).
__device__ __forceinline__ void g2l16(const void* g, void* l) {
    __builtin_amdgcn_global_load_lds(
        (const __attribute__((address_space(1))) unsigned int*)g,
        (__attribute__((address_space(3))) unsigned int*)l,
        16, 0, 0);
}

// ---------------- split weights: f32 -> f16 hi/lo planes ----------------
__global__ __launch_bounds__(256) void split_w_kernel(
    const float* __restrict__ wq, const float* __restrict__ wk,
    _Float16* __restrict__ wq_hi, _Float16* __restrict__ wq_lo,
    _Float16* __restrict__ wk_hi, _Float16* __restrict__ wk_lo)
{
    const float* src = (blockIdx.y == 0) ? wq : wk;
    _Float16* dh     = (blockIdx.y == 0) ? wq_hi : wk_hi;
    _Float16* dl     = (blockIdx.y == 0) ? wq_lo : wk_lo;
    int i4 = blockIdx.x * 256 + threadIdx.x;
    float4 v = ((const float4*)src)[i4];
    half4 vh, vl;
    float c[4] = {v.x, v.y, v.z, v.w};
#pragma unroll
    for (int t = 0; t < 4; t++) {
        _Float16 hi = (_Float16)c[t];
        vh[t] = hi;
        vl[t] = (_Float16)(c[t] - (float)hi);
    }
    ((half4*)dh)[i4] = vh;
    ((half4*)dl)[i4] = vl;
}

// ---------------- wtilde = Wk @ bq ----------------
__global__ __launch_bounds__(256) void wtilde_kernel(
    const float* __restrict__ wk, const float* __restrict__ bq,
    float* __restrict__ wt)
{
    int row  = blockIdx.x * 4 + (threadIdx.x >> 6);
    int lane = threadIdx.x & 63;
    const float4* r4 = (const float4*)(wk + (size_t)row * EMB);
    const float4* b4 = (const float4*)bq;
    float s = 0.f;
#pragma unroll
    for (int j = 0; j < 3; j++) {
        float4 a = r4[lane + j * 64];
        float4 b = b4[lane + j * 64];
        s += a.x * b.x + a.y * b.y + a.z * b.z + a.w * b.w;
    }
#pragma unroll
    for (int sh = 1; sh < 64; sh <<= 1) s += __shfl_xor(s, sh, 64);
    if (lane == 0) wt[row] = s;
}

// ---------------- LayerNorm: f32 in -> f16 hi only, + v = hn . wtilde -------
__global__ __launch_bounds__(256) void ln_kernel(
    const float* __restrict__ h,
    const float* __restrict__ gamma,
    const float* __restrict__ beta,
    const float* __restrict__ wt,
    _Float16* __restrict__ hn_hi,
    float* __restrict__ v_out)
{
    int row  = blockIdx.x * 4 + (threadIdx.x >> 6);
    int lane = threadIdx.x & 63;
    const float4* hr4 = (const float4*)(h + (size_t)row * EMB);
    float4 x[3];
    float s1 = 0.f, s2 = 0.f;
#pragma unroll
    for (int j = 0; j < 3; j++) {
        x[j] = hr4[lane + j * 64];
        s1 += x[j].x + x[j].y + x[j].z + x[j].w;
        s2 += x[j].x * x[j].x + x[j].y * x[j].y + x[j].z * x[j].z + x[j].w * x[j].w;
    }
#pragma unroll
    for (int s = 1; s < 64; s <<= 1) {
        s1 += __shfl_xor(s1, s, 64);
        s2 += __shfl_xor(s2, s, 64);
    }
    float mu  = s1 * (1.0f / EMB);
    float var = s2 * (1.0f / EMB) - mu * mu;
    float rs  = rsqrtf(var + EPS);
    _Float16* oh = hn_hi + (size_t)row * EMB;
    float vsum = 0.f;
#pragma unroll
    for (int j = 0; j < 3; j++) {
        int e4 = lane + j * 64;
        float4 g = ((const float4*)gamma)[e4];
        float4 b = ((const float4*)beta)[e4];
        float4 w = ((const float4*)wt)[e4];
        float v[4] = {
            (x[j].x - mu) * rs * g.x + b.x,
            (x[j].y - mu) * rs * g.y + b.y,
            (x[j].z - mu) * rs * g.z + b.z,
            (x[j].w - mu) * rs * g.w + b.w };
        vsum += v[0] * w.x + v[1] * w.y + v[2] * w.z + v[3] * w.w;
        half4 vh;
#pragma unroll
        for (int t = 0; t < 4; t++) vh[t] = (_Float16)v[t];
        *(half4*)(oh + e4 * 4) = vh;
    }
#pragma unroll
    for (int s = 1; s < 64; s <<= 1) vsum += __shfl_xor(vsum, s, 64);
    if (lane == 0) v_out[row] = vsum;
}

// ---------------- GT = Wk @ Wq^T, f16x2 3-pass, hi/lo split output ----------
__global__ __launch_bounds__(256) void gt_kernel(
    const _Float16* __restrict__ wk_hi, const _Float16* __restrict__ wk_lo,
    const _Float16* __restrict__ wq_hi, const _Float16* __restrict__ wq_lo,
    _Float16* __restrict__ gt_hi, _Float16* __restrict__ gt_lo)
{
    __shared__ __attribute__((aligned(16))) _Float16 Ah_s[BM * BK];
    __shared__ __attribute__((aligned(16))) _Float16 Al_s[BM * BK];
    __shared__ __attribute__((aligned(16))) _Float16 Bh_s[BN * BK];
    __shared__ __attribute__((aligned(16))) _Float16 Bl_s[BN * BK];

    int rowbase = blockIdx.y * BM;
    int colbase = blockIdx.x * BN;
    int tid  = threadIdx.x;
    int lane = tid & 63, wave = tid >> 6;
    int wrow = (wave >> 1) * 64, wcol = (wave & 1) * 64;

    floatx4 acc[4][4];
#pragma unroll
    for (int i = 0; i < 4; i++)
#pragma unroll
        for (int j = 0; j < 4; j++) acc[i][j] = (floatx4){0.f, 0.f, 0.f, 0.f};

    size_t arow = (size_t)(rowbase + tid / 4) * EMB;
    size_t brow = (size_t)(colbase + tid / 4) * EMB;
    int    boff = (tid % 4) * 16;
    const char* gAh = (const char*)(wk_hi + arow) + boff;
    const char* gAl = (const char*)(wk_lo + arow) + boff;
    const char* gBh = (const char*)(wq_hi + brow) + boff;
    const char* gBl = (const char*)(wq_lo + brow) + boff;
    char* lAh = (char*)Ah_s + tid * 16;
    char* lAl = (char*)Al_s + tid * 16;
    char* lBh = (char*)Bh_s + tid * 16;
    char* lBl = (char*)Bl_s + tid * 16;
    const size_t half_stride = (size_t)64 * EMB * 2;

    for (int k0 = 0; k0 < EMB; k0 += BK) {
        __syncthreads();
        g2l16(gAh, lAh); g2l16(gAh + half_stride, lAh + 4096);
        g2l16(gAl, lAl); g2l16(gAl + half_stride, lAl + 4096);
        g2l16(gBh, lBh); g2l16(gBh + half_stride, lBh + 4096);
        g2l16(gBl, lBl); g2l16(gBl + half_stride, lBl + 4096);
        gAh += 64; gAl += 64; gBh += 64; gBl += 64;
        __syncthreads();

        half8 ah[4], al[4], bh[4], bl[4];
#pragma unroll
        for (int i = 0; i < 4; i++) {
            int off = (wrow + i * 16 + (lane & 15)) * 64 + (lane >> 4) * 16;
            ah[i] = *(const half8*)((const char*)Ah_s + off);
            al[i] = *(const half8*)((const char*)Al_s + off);
        }
#pragma unroll
        for (int j = 0; j < 4; j++) {
            int off = (wcol + j * 16 + (lane & 15)) * 64 + (lane >> 4) * 16;
            bh[j] = *(const half8*)((const char*)Bh_s + off);
            bl[j] = *(const half8*)((const char*)Bl_s + off);
        }
#pragma unroll
        for (int i = 0; i < 4; i++)
#pragma unroll
            for (int j = 0; j < 4; j++) {
                acc[i][j] = __builtin_amdgcn_mfma_f32_16x16x32_f16(ah[i], bh[j], acc[i][j], 0, 0, 0);
                acc[i][j] = __builtin_amdgcn_mfma_f32_16x16x32_f16(ah[i], bl[j], acc[i][j], 0, 0, 0);
                acc[i][j] = __builtin_amdgcn_mfma_f32_16x16x32_f16(al[i], bh[j], acc[i][j], 0, 0, 0);
            }
    }

#pragma unroll
    for (int j = 0; j < 4; j++) {
        int col = colbase + wcol + j * 16 + (lane & 15);
#pragma unroll
        for (int i = 0; i < 4; i++) {
#pragma unroll
            for (int r = 0; r < 4; r++) {
                int row = rowbase + wrow + i * 16 + (lane >> 4) * 4 + r;
                float v = acc[i][j][r];
                _Float16 hi = (_Float16)v;
                gt_hi[(size_t)row * EMB + col] = hi;
                gt_lo[(size_t)row * EMB + col] = (_Float16)(v - (float)hi);
            }
        }
    }
}

// ---------------- t = hn_hi @ G  (2-pass), BK=64, t_hi only ----------
__global__ __launch_bounds__(256) void t_kernel(
    const _Float16* __restrict__ hn_hi,
    const _Float16* __restrict__ gt_hi, const _Float16* __restrict__ gt_lo,
    _Float16* __restrict__ t_hi)
{
    __shared__ __attribute__((aligned(16))) _Float16 Ah_s[BM * BK2];
    __shared__ __attribute__((aligned(16))) _Float16 Bh_s[BN * BK2];
    __shared__ __attribute__((aligned(16))) _Float16 Bl_s[BN * BK2];

    int rowbase = blockIdx.y * BM;
    int colbase = blockIdx.x * BN;
    int tid  = threadIdx.x;
    int lane = tid & 63, wave = tid >> 6;
    int wrow = (wave >> 1) * 64, wcol = (wave & 1) * 64;

    floatx4 acc[4][4];
#pragma unroll
    for (int i = 0; i < 4; i++)
#pragma unroll
        for (int j = 0; j < 4; j++) acc[i][j] = (floatx4){0.f, 0.f, 0.f, 0.f};

    // staging: 128 rows x 128 B per plane; thread covers row tid/8, byte (tid%8)*16, 4 passes of 32 rows
    size_t arow = (size_t)(rowbase + tid / 8) * EMB;
    size_t brow = (size_t)(colbase + tid / 8) * EMB;
    int    boff = (tid % 8) * 16;
    const char* gAh = (const char*)(hn_hi + arow) + boff;
    const char* gBh = (const char*)(gt_hi + brow) + boff;
    const char* gBl = (const char*)(gt_lo + brow) + boff;
    char* lAh = (char*)Ah_s + tid * 16;
    char* lBh = (char*)Bh_s + tid * 16;
    char* lBl = (char*)Bl_s + tid * 16;
    const size_t pstride = (size_t)32 * EMB * 2;   // 32 rows of f16

    for (int k0 = 0; k0 < EMB; k0 += BK2) {
        __syncthreads();
#pragma unroll
        for (int p = 0; p < 4; p++) {
            g2l16(gAh + p * pstride, lAh + p * 4096);
            g2l16(gBh + p * pstride, lBh + p * 4096);
            g2l16(gBl + p * pstride, lBl + p * 4096);
        }
        gAh += 128; gBh += 128; gBl += 128;
        __syncthreads();

#pragma unroll
        for (int ko = 0; ko < 2; ko++) {
            half8 ah[4], bh[4], bl[4];
#pragma unroll
            for (int i = 0; i < 4; i++) {
                int off = (wrow + i * 16 + (lane & 15)) * 128 + ko * 64 + (lane >> 4) * 16;
                ah[i] = *(const half8*)((const char*)Ah_s + off);
            }
#pragma unroll
            for (int j = 0; j < 4; j++) {
                int off = (wcol + j * 16 + (lane & 15)) * 128 + ko * 64 + (lane >> 4) * 16;
                bh[j] = *(const half8*)((const char*)Bh_s + off);
                bl[j] = *(const half8*)((const char*)Bl_s + off);
            }
#pragma unroll
            for (int i = 0; i < 4; i++)
#pragma unroll
                for (int j = 0; j < 4; j++) {
                    acc[i][j] = __builtin_amdgcn_mfma_f32_16x16x32_f16(ah[i], bh[j], acc[i][j], 0, 0, 0);
                    acc[i][j] = __builtin_amdgcn_mfma_f32_16x16x32_f16(ah[i], bl[j], acc[i][j], 0, 0, 0);
                }
        }
    }

#pragma unroll
    for (int j = 0; j < 4; j++) {
        int col = colbase + wcol + j * 16 + (lane & 15);
#pragma unroll
        for (int i = 0; i < 4; i++) {
#pragma unroll
            for (int r = 0; r < 4; r++) {
                int row = rowbase + wrow + i * 16 + (lane >> 4) * 4 + r;
                t_hi[(size_t)row * EMB + col] = (_Float16)acc[i][j][r];
            }
        }
    }
}

// ---------------- scores: s = t_hi @ hn_hi^T + v_c, 1-pass, BK=64 + softmax partial
__global__ __launch_bounds__(256) void scores_kernel(
    const _Float16* __restrict__ t_hi,
    const _Float16* __restrict__ hn_hi,
    const float* __restrict__ v_in,
    float* __restrict__ out,
    float2* __restrict__ state)
{
    __shared__ __attribute__((aligned(16))) _Float16 Ah_s[BM * BK2];
    __shared__ __attribute__((aligned(16))) _Float16 Bh_s[BN * BK2];
    __shared__ float red[128][2];

    int b = blockIdx.z;
    size_t base = (size_t)b * SEQ * EMB;
    int rowbase = blockIdx.y * BM;
    int colbase = blockIdx.x * BN;
    int tid  = threadIdx.x;
    int lane = tid & 63, wave = tid >> 6;
    int wrow = (wave >> 1) * 64, wcol = (wave & 1) * 64;

    floatx4 acc[4][4];
#pragma unroll
    for (int i = 0; i < 4; i++)
#pragma unroll
        for (int j = 0; j < 4; j++) acc[i][j] = (floatx4){0.f, 0.f, 0.f, 0.f};

    size_t arow = base + (size_t)(rowbase + tid / 8) * EMB;
    size_t brow = base + (size_t)(colbase + tid / 8) * EMB;
    int    boff = (tid % 8) * 16;
    const char* gAh = (const char*)(t_hi + arow) + boff;
    const char* gBh = (const char*)(hn_hi + brow) + boff;
    char* lAh = (char*)Ah_s + tid * 16;
    char* lBh = (char*)Bh_s + tid * 16;
    const size_t pstride = (size_t)32 * EMB * 2;

    for (int k0 = 0; k0 < EMB; k0 += BK2) {
        __syncthreads();
#pragma unroll
        for (int p = 0; p < 4; p++) {
            g2l16(gAh + p * pstride, lAh + p * 4096);
            g2l16(gBh + p * pstride, lBh + p * 4096);
        }
        gAh += 128; gBh += 128;
        __syncthreads();

#pragma unroll
        for (int ko = 0; ko < 2; ko++) {
            half8 ah[4], bh[4];
#pragma unroll
            for (int i = 0; i < 4; i++) {
                int off = (wrow + i * 16 + (lane & 15)) * 128 + ko * 64 + (lane >> 4) * 16;
                ah[i] = *(const half8*)((const char*)Ah_s + off);
            }
#pragma unroll
            for (int j = 0; j < 4; j++) {
                int off = (wcol + j * 16 + (lane & 15)) * 128 + ko * 64 + (lane >> 4) * 16;
                bh[j] = *(const half8*)((const char*)Bh_s + off);
            }
#pragma unroll
            for (int i = 0; i < 4; i++)
#pragma unroll
                for (int j = 0; j < 4; j++)
                    acc[i][j] = __builtin_amdgcn_mfma_f32_16x16x32_f16(ah[i], bh[j], acc[i][j], 0, 0, 0);
        }
    }

    // add column term v_c
    const float* vb = v_in + (size_t)b * SEQ + colbase;
#pragma unroll
    for (int j = 0; j < 4; j++) {
        float vv = vb[wcol + j * 16 + (lane & 15)];
#pragma unroll
        for (int i = 0; i < 4; i++)
#pragma unroll
            for (int r = 0; r < 4; r++) acc[i][j][r] += vv;
    }

    // ---- softmax partial epilogue ----
    float m1[4][4];
#pragma unroll
    for (int i = 0; i < 4; i++)
#pragma unroll
        for (int r = 0; r < 4; r++) {
            float m = fmaxf(fmaxf(acc[i][0][r], acc[i][1][r]), fmaxf(acc[i][2][r], acc[i][3][r]));
#pragma unroll
            for (int s = 1; s < 16; s <<= 1) m = fmaxf(m, __shfl_xor(m, s, 64));
            m1[i][r] = m;
        }
    if ((lane & 15) == 0) {
#pragma unroll
        for (int i = 0; i < 4; i++)
#pragma unroll
            for (int r = 0; r < 4; r++)
                red[wrow + i * 16 + (lane >> 4) * 4 + r][wave & 1] = m1[i][r];
    }
    __syncthreads();
    float mrow[4][4];
#pragma unroll
    for (int i = 0; i < 4; i++)
#pragma unroll
        for (int r = 0; r < 4; r++) {
            int rr = wrow + i * 16 + (lane >> 4) * 4 + r;
            mrow[i][r] = fmaxf(red[rr][0], red[rr][1]);
        }
    __syncthreads();

    float ls[4][4];
#pragma unroll
    for (int i = 0; i < 4; i++)
#pragma unroll
        for (int r = 0; r < 4; r++) {
            float s = 0.f;
#pragma unroll
            for (int j = 0; j < 4; j++) {
                float e = __expf(acc[i][j][r] - mrow[i][r]);
                acc[i][j][r] = e;
                s += e;
            }
#pragma unroll
            for (int sh = 1; sh < 16; sh <<= 1) s += __shfl_xor(s, sh, 64);
            ls[i][r] = s;
        }
    if ((lane & 15) == 0) {
#pragma unroll
        for (int i = 0; i < 4; i++)
#pragma unroll
            for (int r = 0; r < 4; r++)
                red[wrow + i * 16 + (lane >> 4) * 4 + r][wave & 1] = ls[i][r];
    }
    __syncthreads();

    // write ptilde (f32)
    size_t outbase = (size_t)b * SEQ * SEQ;
#pragma unroll
    for (int i = 0; i < 4; i++)
#pragma unroll
        for (int j = 0; j < 4; j++)
#pragma unroll
            for (int r = 0; r < 4; r++) {
                int row = rowbase + wrow + i * 16 + (lane >> 4) * 4 + r;
                int col = colbase + wcol + j * 16 + (lane & 15);
                out[outbase + (size_t)row * SEQ + col] = acc[i][j][r];
            }

    // write per-(row, colblock) state
    if ((wave & 1) == 0 && (lane & 15) == 0) {
#pragma unroll
        for (int i = 0; i < 4; i++)
#pragma unroll
            for (int r = 0; r < 4; r++) {
                int rr = wrow + i * 16 + (lane >> 4) * 4 + r;
                float l = red[rr][0] + red[rr][1];
                state[((size_t)b * SEQ + rowbase + rr) * 16 + blockIdx.x] =
                    make_float2(mrow[i][r], l);
            }
    }
}

// ---------------- fixup: global softmax normalize ----------------
__global__ __launch_bounds__(256) void fixup_kernel(
    float* __restrict__ out,
    const float2* __restrict__ state)
{
    int row  = blockIdx.x * 4 + (threadIdx.x >> 6);
    int lane = threadIdx.x & 63;
    const float2* st = state + (size_t)row * 16;
    float m[16], l[16];
    float M = -INFINITY;
#pragma unroll
    for (int t = 0; t < 16; t++) { float2 v = st[t]; m[t] = v.x; l[t] = v.y; M = fmaxf(M, m[t]); }
    float L = 0.f;
#pragma unroll
    for (int t = 0; t < 16; t++) { m[t] = __expf(m[t] - M); L += l[t] * m[t]; }
    float inv = 1.0f / L;
    float4* o4 = (float4*)(out + (size_t)row * SEQ);
#pragma unroll
    for (int c0 = 0; c0 < 8; c0++) {
        int i4 = c0 * 64 + lane;
        float s = m[i4 >> 5] * inv;
        float4 v = o4[i4];
        v.x *= s; v.y *= s; v.z *= s; v.w *= s;
        o4[i4] = v;
    }
}

extern "C" void kernel_launch(void* const* d_in, const int* in_sizes, int n_in,
                              void* d_out, int out_size, void* d_ws, size_t ws_size,
                              hipStream_t stream)
{
    const float* h  = (const float*)d_in[0];
    const float* g  = (const float*)d_in[1];
    const float* be = (const float*)d_in[2];
    const float* wq = (const float*)d_in[3];
    const float* bq = (const float*)d_in[4];
    const float* wk = (const float*)d_in[5];
    const float* bk = (const float*)d_in[6];
    (void)bk;  // bk contributes only softmax-invariant row/const terms
    float* out = (float*)d_out;

    char* ws = (char*)d_ws;
    const size_t SZ  = (size_t)ROWS * EMB * 2;         // 25,165,824 B per 16384x768 f16 plane
    const size_t WSZ = (size_t)EMB * EMB * 2;          // 1,179,648 B per 768x768 f16 plane
    _Float16* hn_hi = (_Float16*)(ws);
    _Float16* t_hi  = (_Float16*)(ws + SZ);
    char* wbase = ws + 2 * SZ;
    _Float16* wq_hi = (_Float16*)(wbase);
    _Float16* wq_lo = (_Float16*)(wbase + WSZ);
    _Float16* wk_hi = (_Float16*)(wbase + 2 * WSZ);
    _Float16* wk_lo = (_Float16*)(wbase + 3 * WSZ);
    _Float16* gt_hi = (_Float16*)(wbase + 4 * WSZ);
    _Float16* gt_lo = (_Float16*)(wbase + 5 * WSZ);
    char* sbase = wbase + 6 * WSZ;
    float*  wt = (float*)(sbase);                      // 768 f32
    float*  v  = (float*)(sbase + 4096);               // 16384 f32
    float2* st = (float2*)(sbase + 4096 + 65536);      // 2 MB

    split_w_kernel<<<dim3(576, 2), 256, 0, stream>>>(wq, wk, wq_hi, wq_lo, wk_hi, wk_lo);
    wtilde_kernel<<<dim3(EMB / 4), 256, 0, stream>>>(wk, bq, wt);
    ln_kernel<<<dim3(ROWS / 4), 256, 0, stream>>>(h, g, be, wt, hn_hi, v);
    gt_kernel<<<dim3(EMB / BN, EMB / BM), 256, 0, stream>>>(wk_hi, wk_lo, wq_hi, wq_lo, gt_hi, gt_lo);
    t_kernel<<<dim3(EMB / BN, ROWS / BM), 256, 0, stream>>>(hn_hi, gt_hi, gt_lo, t_hi);
    scores_kernel<<<dim3(SEQ / BN, SEQ / BM, BATCH), 256, 0, stream>>>(t_hi, hn_hi, v, out, st);
    fixup_kernel<<<dim3(ROWS / 4), 256, 0, stream>>>(out, st);
}